// Round 7
// baseline (924.712 us; speedup 1.0000x reference)
//
#include <hip/hip_runtime.h>
#include <hip/hip_bf16.h>
#include <math.h>

#define B_   4
#define T_   2048
#define C_   2048
#define NH_  16
#define HD_  128
#define KVD_ 1024

typedef __attribute__((ext_vector_type(4))) float f32x4;
typedef __attribute__((ext_vector_type(16))) float f32x16;
typedef __attribute__((ext_vector_type(8))) short bf16x8;
typedef __attribute__((ext_vector_type(4))) unsigned int u32x4;

__device__ __forceinline__ void async_copy16(const __hip_bfloat16* g, __hip_bfloat16* l) {
  __builtin_amdgcn_global_load_lds((const __attribute__((address_space(1))) void*)g,
                                   (__attribute__((address_space(3))) void*)l,
                                   16, 0, 0);
}

__device__ __forceinline__ float bf2f(__hip_bfloat16 h) { return __bfloat162float(h); }

// pack two f32 -> one dword of 2 bf16 (a in low half)
__device__ __forceinline__ unsigned int pkbf(float a, float b) {
  float2 f2; f2.x = a; f2.y = b;
  __hip_bfloat162 h2 = __float22bfloat162_rn(f2);
  return *reinterpret_cast<unsigned int*>(&h2);
}

// ---------------- f32 -> bf16 convert (x) ----------------
__global__ __launch_bounds__(256) void f32_to_bf16_k(const float* __restrict__ src,
                                                     __hip_bfloat16* __restrict__ dst, int n4) {
  int i = blockIdx.x * 256 + threadIdx.x;
  if (i >= n4) return;
  float4 f = ((const float4*)src)[i];
  __hip_bfloat16 o[4] = {__float2bfloat16(f.x), __float2bfloat16(f.y),
                         __float2bfloat16(f.z), __float2bfloat16(f.w)};
  *(uint2*)(dst + (size_t)i * 4) = *(uint2*)o;
}

// ---------------- transpose + convert: WT[n][k] = bf16(W[k][n]) ----------------
__global__ __launch_bounds__(256) void transpose_f32_bf16_k(const float* __restrict__ W,
                                                            __hip_bfloat16* __restrict__ WT,
                                                            int K, int N) {
  __shared__ float tile[32][33];
  int bx = blockIdx.x * 32;  // n
  int by = blockIdx.y * 32;  // k
  int tx = threadIdx.x, ty = threadIdx.y;
  for (int i = ty; i < 32; i += 8)
    tile[i][tx] = W[(size_t)(by + i) * N + (bx + tx)];
  __syncthreads();
  for (int i = ty; i < 32; i += 8)
    WT[(size_t)(bx + i) * K + (by + tx)] = __float2bfloat16(tile[tx][i]);
}

// ---------------- V transpose: Vt[b][g][d][perm(t)] = kv[b][t][512 + g*128 + d] --------
// perm swaps bits 2<->3 of t within each 16-group (see attn_k P layout).
__global__ __launch_bounds__(256) void vtrans_k(const __hip_bfloat16* __restrict__ kv,
                                                __hip_bfloat16* __restrict__ vt) {
  __shared__ __hip_bfloat16 tile[32][33];
  int bg = blockIdx.z;            // b*4+g
  int d0 = blockIdx.y * 32;
  int t0 = blockIdx.x * 32;
  int tx = threadIdx.x, ty = threadIdx.y;
  int b = bg >> 2, g = bg & 3;
  const __hip_bfloat16* src = kv + (size_t)b * T_ * KVD_ + 512 + g * HD_;
  for (int i = ty; i < 32; i += 8)
    tile[i][tx] = src[(size_t)(t0 + i) * KVD_ + d0 + tx];
  __syncthreads();
  __hip_bfloat16* dst = vt + (size_t)bg * HD_ * T_;
  int txp = (tx & ~12) | ((tx & 4) << 1) | ((tx & 8) >> 1);  // swap bits 2,3
  for (int i = ty; i < 32; i += 8)
    dst[(size_t)(d0 + i) * T_ + t0 + txp] = tile[tx][i];
}

// ---------------- row l2norm (in place, bf16), scale folded via `extra` ----------------
template<int PER>
__global__ __launch_bounds__(256) void rownorm_k(__hip_bfloat16* __restrict__ buf,
                                                 int stride, float extra) {
  const int tid = threadIdx.x;
  __hip_bfloat16* p = buf + (size_t)blockIdx.x * stride;
  float v[PER];
  float ss = 0.f;
  #pragma unroll
  for (int e = 0; e < PER; ++e) { v[e] = bf2f(p[tid + e * 256]); ss += v[e] * v[e]; }
  #pragma unroll
  for (int off = 32; off >= 1; off >>= 1) ss += __shfl_xor(ss, off, 64);
  __shared__ float wsum[4];
  if ((tid & 63) == 0) wsum[tid >> 6] = ss;
  __syncthreads();
  float tot = wsum[0] + wsum[1] + wsum[2] + wsum[3];
  float sc = extra / (sqrtf(tot) + 1e-12f);
  #pragma unroll
  for (int e = 0; e < PER; ++e) p[tid + e * 256] = __float2bfloat16(v[e] * sc);
}

// ---------------- GEMM v2: ring-3 LDS, counted-vmcnt pipeline (unchanged from R5) ------
template<typename OutT>
__global__ __launch_bounds__(512, 2) void gemm3_k(const __hip_bfloat16* __restrict__ A,
                                                  const __hip_bfloat16* __restrict__ BT,
                                                  OutT* __restrict__ Cc,
                                                  int M, int N, int K) {
  __shared__ alignas(16) __hip_bfloat16 As[3][128 * 64];
  __shared__ alignas(16) __hip_bfloat16 Bs[3][256 * 64];
  const int tid  = threadIdx.x;
  const int bm   = blockIdx.y * 128;
  const int bn   = blockIdx.x * 256;
  const int wave = tid >> 6, lane = tid & 63;
  const int wm = wave >> 2, wn = wave & 3;
  const int lm = lane & 15, quad = lane >> 4;
  const size_t Kz = (size_t)K;
  const int NT = K >> 6;

  const int srow = tid >> 3;                        // 0..63
  const int csw  = ((tid & 7) ^ (srow & 7)) * 8;    // swizzled 16B chunk offset
  const __hip_bfloat16* aSrc0 = A  + (size_t)(bm + srow) * Kz + csw;
  const __hip_bfloat16* aSrc1 = A  + (size_t)(bm + 64 + srow) * Kz + csw;
  const __hip_bfloat16* bSrc0 = BT + (size_t)(bn + srow) * Kz + csw;
  const __hip_bfloat16* bSrc1 = BT + (size_t)(bn + 64 + srow) * Kz + csw;
  const __hip_bfloat16* bSrc2 = BT + (size_t)(bn + 128 + srow) * Kz + csw;
  const __hip_bfloat16* bSrc3 = BT + (size_t)(bn + 192 + srow) * Kz + csw;

  auto stageA = [&](int slot, int koff) {
    async_copy16(aSrc0 + koff, As[slot] + tid * 8);
    async_copy16(aSrc1 + koff, As[slot] + (512 + tid) * 8);
  };
  auto stageB0 = [&](int slot, int koff) {
    async_copy16(bSrc0 + koff, Bs[slot] + tid * 8);
  };
  auto stageB123 = [&](int slot, int koff) {
    async_copy16(bSrc1 + koff, Bs[slot] + (512 + tid) * 8);
    async_copy16(bSrc2 + koff, Bs[slot] + (1024 + tid) * 8);
    async_copy16(bSrc3 + koff, Bs[slot] + (1536 + tid) * 8);
  };

  const int ch0 = ((quad) ^ (lm & 7)) * 8;
  const int ch1 = ((4 + quad) ^ (lm & 7)) * 8;
  const int arow = wm * 64 + lm;
  const int brow = wn * 64 + lm;

  f32x4 acc[4][4] = {};

  stageA(0, 0); stageB0(0, 0); stageB123(0, 0);
  if (NT > 1) { stageA(1, 64); stageB0(1, 64); stageB123(1, 64); }

  int s = 0;
  for (int t = 0; t < NT; ++t) {
    const int sn = (s + 2 > 2) ? (s - 1) : (s + 2);   // (s+2)%3
    const bool pre = (t + 2) < NT;
    const int koff = (t + 2) * 64;
    if (t + 1 < NT) asm volatile("s_waitcnt vmcnt(6)" ::: "memory");
    else            asm volatile("s_waitcnt vmcnt(0)" ::: "memory");
    __builtin_amdgcn_s_barrier();
    bf16x8 af[4][2], bf0[2][2];
    #pragma unroll
    for (int mf = 0; mf < 4; ++mf) {
      af[mf][0] = *(const bf16x8*)(As[s] + (arow + mf * 16) * 64 + ch0);
      af[mf][1] = *(const bf16x8*)(As[s] + (arow + mf * 16) * 64 + ch1);
    }
    #pragma unroll
    for (int nf = 0; nf < 2; ++nf) {
      bf0[nf][0] = *(const bf16x8*)(Bs[s] + (brow + nf * 16) * 64 + ch0);
      bf0[nf][1] = *(const bf16x8*)(Bs[s] + (brow + nf * 16) * 64 + ch1);
    }
    if (pre) { stageA(sn, koff); stageB0(sn, koff); }
    __builtin_amdgcn_s_barrier();
    __builtin_amdgcn_s_setprio(1);
    #pragma unroll
    for (int mf = 0; mf < 4; ++mf)
      #pragma unroll
      for (int nf = 0; nf < 2; ++nf) {
        acc[mf][nf] = __builtin_amdgcn_mfma_f32_16x16x32_bf16(af[mf][0], bf0[nf][0], acc[mf][nf], 0, 0, 0);
        acc[mf][nf] = __builtin_amdgcn_mfma_f32_16x16x32_bf16(af[mf][1], bf0[nf][1], acc[mf][nf], 0, 0, 0);
      }
    __builtin_amdgcn_s_setprio(0);
    __builtin_amdgcn_s_barrier();
    bf16x8 bf1[2][2];
    #pragma unroll
    for (int nf = 0; nf < 2; ++nf) {
      bf1[nf][0] = *(const bf16x8*)(Bs[s] + (brow + (nf + 2) * 16) * 64 + ch0);
      bf1[nf][1] = *(const bf16x8*)(Bs[s] + (brow + (nf + 2) * 16) * 64 + ch1);
    }
    if (pre) stageB123(sn, koff);
    __builtin_amdgcn_s_barrier();
    __builtin_amdgcn_s_setprio(1);
    #pragma unroll
    for (int mf = 0; mf < 4; ++mf)
      #pragma unroll
      for (int nf = 0; nf < 2; ++nf) {
        acc[mf][nf + 2] = __builtin_amdgcn_mfma_f32_16x16x32_bf16(af[mf][0], bf1[nf][0], acc[mf][nf + 2], 0, 0, 0);
        acc[mf][nf + 2] = __builtin_amdgcn_mfma_f32_16x16x32_bf16(af[mf][1], bf1[nf][1], acc[mf][nf + 2], 0, 0, 0);
      }
    __builtin_amdgcn_s_setprio(0);
    s = (s == 2) ? 0 : s + 1;
  }

  const int r0 = quad * 4;
  #pragma unroll
  for (int mf = 0; mf < 4; ++mf)
    #pragma unroll
    for (int nf = 0; nf < 4; ++nf)
      #pragma unroll
      for (int r = 0; r < 4; ++r) {
        int gr = bm + wm * 64 + mf * 16 + r0 + r;
        int gc = bn + wn * 64 + nf * 16 + lm;
        float v = acc[mf][nf][r];
        if constexpr (__is_same(OutT, float))
          Cc[(size_t)gr * N + gc] = v;
        else
          Cc[(size_t)gr * N + gc] = __float2bfloat16(v);
      }
}

// ---------------- flash attention v8: v6 core + V-from-global + 4 blocks/CU ----------
// 256 threads (4 waves x 32 q-rows), swapped QK^T 32x32x16, P fully in-register via
// bit-2/3-swapped V layout, bounded scores. Changes vs v6 (R5, 111us):
//  * V is NOT staged in LDS: the (b,g) V panel is 512KB, shared by 32 blocks -> L2
//    resident. PV B-frags load direct from global: vb + (ct*32+l31)*T + j0 + (2kc+hi)*8
//    (identical bytes the old swizzled LDS read returned). L2 latency hides under QK.
//  * LDS halves to 32KB (K double-buffer only) -> __launch_bounds__(256,4): 4 resident
//    blocks/CU = 4 waves/SIMD of INDEPENDENT blocks (R6 showed intra-block waves
//    serialize on the shared barrier; independent blocks don't).
//  * Triangle unfolded (grid x = 16 q-tiles, 1024 blocks, heavy-first): 4-deep
//    residency gives the scheduler slack to smooth the triangular imbalance.
__global__ __launch_bounds__(256, 4) void attn_k(const __hip_bfloat16* __restrict__ q,
                                                 const __hip_bfloat16* __restrict__ kv,
                                                 const __hip_bfloat16* __restrict__ vt,
                                                 __hip_bfloat16* __restrict__ y) {
  const int qt = (int)gridDim.x - 1 - (int)blockIdx.x;  // heavy blocks first
  const int h  = blockIdx.y;
  const int b  = blockIdx.z;
  const int g  = h >> 2;
  const int tid = threadIdx.x;
  const int wave = tid >> 6, lane = tid & 63;
  const int l31 = lane & 31, hi = lane >> 5;
  const int qbase = qt * 128 + wave * 32;
  const int qmax = qbase + 31;
  const int ntiles = 2 * qt + 2;

  // K tiles XOR-swizzled in LDS: chunk (row,c) holds global chunk c^(row&15).
  __shared__ alignas(16) __hip_bfloat16 Ks[2][64 * 128];

  const __hip_bfloat16* kb = kv + (size_t)b * T_ * KVD_ + g * HD_;
  const __hip_bfloat16* vb = vt + (size_t)(b * 4 + g) * HD_ * T_;

  auto stage = [&](int buf, int jt) {
    const size_t j1 = (size_t)jt * 64;
    #pragma unroll
    for (int e = 0; e < 4; ++e) {
      int idx = tid + e * 256;
      int row = idx >> 4, c = idx & 15;
      async_copy16(kb + (j1 + row) * KVD_ + ((c ^ (row & 15)) * 8), Ks[buf] + idx * 8);
    }
  };

  stage(0, 0);

  // Q -> registers (one row per lane&31; hi half picks the 8-elem sub-chunk)
  const __hip_bfloat16* qrow = q + ((size_t)b * T_ + qbase + l31) * C_ + h * HD_;
  bf16x8 qf[8];
  #pragma unroll
  for (int kc = 0; kc < 8; ++kc)
    qf[kc] = *(const bf16x8*)(qrow + kc * 16 + hi * 8);

  // V row base pointers (global, bit-2/3-swapped layout from vtrans_k)
  const __hip_bfloat16* vrow[4];
  #pragma unroll
  for (int ct = 0; ct < 4; ++ct)
    vrow[ct] = vb + (size_t)(ct * 32 + l31) * T_;

  __syncthreads();  // tile 0 staged (barrier drains vmcnt)

  f32x16 o_acc[4] = {};
  float l_acc = 0.f;

  for (int it = 0; it < ntiles; ++it) {
    const int cur = it & 1;
    if (it + 1 < ntiles) stage(cur ^ 1, it + 1);
    const int j0 = it * 64;
    if (j0 <= qmax) {  // wave-uniform: skip fully-masked tiles
      // ---- S^T = K Q^T : acc layout col=lane&31=q-row, row=kv-local ----
      f32x16 st0 = {}, st1 = {};
      __builtin_amdgcn_s_setprio(1);
      #pragma unroll
      for (int kc = 0; kc < 8; ++kc) {
        const int cs0 = (((2 * kc + hi) ^ (l31 & 15)) * 8);
        bf16x8 k0 = *(const bf16x8*)(Ks[cur] + l31 * 128 + cs0);
        bf16x8 k1 = *(const bf16x8*)(Ks[cur] + (32 + l31) * 128 + cs0);
        st0 = __builtin_amdgcn_mfma_f32_32x32x16_bf16(k0, qf[kc], st0, 0, 0, 0);
        st1 = __builtin_amdgcn_mfma_f32_32x32x16_bf16(k1, qf[kc], st1, 0, 0, 0);
      }
      __builtin_amdgcn_s_setprio(0);
      // ---- P = exp(S) + causal mask; per-lane only (q row = lane&31) ----
      const int qd = qbase + l31 - j0;  // kv_local <= qd is unmasked
      if (j0 + 63 <= qbase) {           // tile fully unmasked: skip compares
        #pragma unroll
        for (int r = 0; r < 16; ++r) {
          float p0 = __expf(st0[r]);
          float p1 = __expf(st1[r]);
          st0[r] = p0; st1[r] = p1;
          l_acc += p0 + p1;
        }
      } else {
        #pragma unroll
        for (int r = 0; r < 16; ++r) {
          const int ofs = (r & 3) + 8 * (r >> 2) + 4 * hi;  // kv_local (kt=0)
          float p0 = (ofs <= qd) ? __expf(st0[r]) : 0.f;
          float p1 = (ofs + 32 <= qd) ? __expf(st1[r]) : 0.f;
          st0[r] = p0; st1[r] = p1;
          l_acc += p0 + p1;
        }
      }
      // ---- pack P -> bf16 words W[m][i]; m = kv-group (8 kv), i = word ----
      unsigned int W[8][2];
      #pragma unroll
      for (int q4 = 0; q4 < 4; ++q4) {
        W[q4][0]     = pkbf(st0[4 * q4 + 0], st0[4 * q4 + 1]);
        W[q4][1]     = pkbf(st0[4 * q4 + 2], st0[4 * q4 + 3]);
        W[4 + q4][0] = pkbf(st1[4 * q4 + 0], st1[4 * q4 + 1]);
        W[4 + q4][1] = pkbf(st1[4 * q4 + 2], st1[4 * q4 + 3]);
      }
      // ---- O += P V (V frags direct from global; kv axis permuted in both) ----
      __builtin_amdgcn_s_setprio(1);
      #pragma unroll
      for (int kc = 0; kc < 4; ++kc) {
        u32x4 pw;
        pw[0] = W[2 * kc][0]; pw[1] = W[2 * kc][1];
        pw[2] = W[2 * kc + 1][0]; pw[3] = W[2 * kc + 1][1];
        bf16x8 pf = __builtin_bit_cast(bf16x8, pw);
        const int vofs = j0 + (2 * kc + hi) * 8;
        #pragma unroll
        for (int ct = 0; ct < 4; ++ct) {
          bf16x8 vf = *(const bf16x8*)(vrow[ct] + vofs);
          o_acc[ct] = __builtin_amdgcn_mfma_f32_32x32x16_bf16(pf, vf, o_acc[ct], 0, 0, 0);
        }
      }
      __builtin_amdgcn_s_setprio(0);
    }
    __syncthreads();  // drains prefetch vmcnt + protects buffer swap
  }

  // ---- epilogue: finish row sums (other hi half), divide, store ----
  float lsum = l_acc + __shfl_xor(l_acc, 32, 64);
  __hip_bfloat16* yb = y + ((size_t)b * T_ + qbase) * C_ + h * HD_ + l31;
  #pragma unroll
  for (int ct = 0; ct < 4; ++ct)
    #pragma unroll
    for (int r = 0; r < 16; ++r) {
      int row = (r & 3) + 8 * (r >> 2) + 4 * hi;
      float linv = 1.0f / __shfl(lsum, row, 64);
      yb[(size_t)row * C_ + ct * 32] = __float2bfloat16(o_acc[ct][r] * linv);
    }
}

extern "C" void kernel_launch(void* const* d_in, const int* in_sizes, int n_in,
                              void* d_out, int out_size, void* d_ws, size_t ws_size,
                              hipStream_t stream) {
  (void)in_sizes; (void)n_in; (void)out_size; (void)ws_size;
  const float* x     = (const float*)d_in[0];
  const float* Wq    = (const float*)d_in[1];
  const float* Wkv   = (const float*)d_in[2];
  const float* Wproj = (const float*)d_in[3];
  char* ws = (char*)d_ws;
  __hip_bfloat16* xb     = (__hip_bfloat16*)(ws);               // 32 MB (reused as y)
  __hip_bfloat16* WqT    = (__hip_bfloat16*)(ws + 33554432);    //  8 MB
  __hip_bfloat16* WkvT   = (__hip_bfloat16*)(ws + 41943040);    //  4 MB
  __hip_bfloat16* WprojT = (__hip_bfloat16*)(ws + 46137344);    //  8 MB
  __hip_bfloat16* qn     = (__hip_bfloat16*)(ws + 54525952);    // 32 MB
  __hip_bfloat16* kvb    = (__hip_bfloat16*)(ws + 88080384);    // 16 MB
  __hip_bfloat16* y      = xb;                                  // alias: xb dead after kv-gemm
  __hip_bfloat16* vt     = (__hip_bfloat16*)d_out;              // 16 MB scratch in d_out
  float* out             = (float*)d_out;

  f32_to_bf16_k<<<16384, 256, 0, stream>>>(x, xb, 4194304);
  transpose_f32_bf16_k<<<dim3(64, 64), dim3(32, 8), 0, stream>>>(Wq, WqT, 2048, 2048);
  transpose_f32_bf16_k<<<dim3(32, 64), dim3(32, 8), 0, stream>>>(Wkv, WkvT, 2048, 1024);
  transpose_f32_bf16_k<<<dim3(64, 64), dim3(32, 8), 0, stream>>>(Wproj, WprojT, 2048, 2048);
  gemm3_k<__hip_bfloat16><<<dim3(8, 64), 512, 0, stream>>>(xb, WqT, qn, 8192, 2048, 2048);
  gemm3_k<__hip_bfloat16><<<dim3(4, 64), 512, 0, stream>>>(xb, WkvT, kvb, 8192, 1024, 2048);
  rownorm_k<8><<<8192, 256, 0, stream>>>(qn, 2048, 0.08838834764831845f);  // 1/sqrt(HD) folded
  rownorm_k<2><<<8192, 256, 0, stream>>>(kvb, 1024, 1.0f);
  vtrans_k<<<dim3(64, 4, 16), dim3(32, 8), 0, stream>>>(kvb, vt);
  attn_k<<<dim3(16, 16, 4), 256, 0, stream>>>(qn, kvb, vt, y);
  gemm3_k<float><<<dim3(8, 64), 512, 0, stream>>>(y, WprojT, out, 8192, 2048, 2048);
}

// Round 8
// 642.718 us; speedup vs baseline: 1.4388x; 1.4388x over previous
//
#include <hip/hip_runtime.h>
#include <hip/hip_bf16.h>
#include <math.h>

#define B_   4
#define T_   2048
#define C_   2048
#define NH_  16
#define HD_  128
#define KVD_ 1024

typedef __attribute__((ext_vector_type(4))) float f32x4;
typedef __attribute__((ext_vector_type(16))) float f32x16;
typedef __attribute__((ext_vector_type(8))) short bf16x8;
typedef __attribute__((ext_vector_type(4))) unsigned int u32x4;

__device__ __forceinline__ void async_copy16(const __hip_bfloat16* g, __hip_bfloat16* l) {
  __builtin_amdgcn_global_load_lds((const __attribute__((address_space(1))) void*)g,
                                   (__attribute__((address_space(3))) void*)l,
                                   16, 0, 0);
}

__device__ __forceinline__ float bf2f(__hip_bfloat16 h) { return __bfloat162float(h); }

// pack two f32 -> one dword of 2 bf16 (a in low half)
__device__ __forceinline__ unsigned int pkbf(float a, float b) {
  float2 f2; f2.x = a; f2.y = b;
  __hip_bfloat162 h2 = __float22bfloat162_rn(f2);
  return *reinterpret_cast<unsigned int*>(&h2);
}

// ---------------- f32 -> bf16 convert (x) ----------------
__global__ __launch_bounds__(256) void f32_to_bf16_k(const float* __restrict__ src,
                                                     __hip_bfloat16* __restrict__ dst, int n4) {
  int i = blockIdx.x * 256 + threadIdx.x;
  if (i >= n4) return;
  float4 f = ((const float4*)src)[i];
  __hip_bfloat16 o[4] = {__float2bfloat16(f.x), __float2bfloat16(f.y),
                         __float2bfloat16(f.z), __float2bfloat16(f.w)};
  *(uint2*)(dst + (size_t)i * 4) = *(uint2*)o;
}

// ---------------- transpose + convert: WT[n][k] = bf16(W[k][n]) ----------------
__global__ __launch_bounds__(256) void transpose_f32_bf16_k(const float* __restrict__ W,
                                                            __hip_bfloat16* __restrict__ WT,
                                                            int K, int N) {
  __shared__ float tile[32][33];
  int bx = blockIdx.x * 32;  // n
  int by = blockIdx.y * 32;  // k
  int tx = threadIdx.x, ty = threadIdx.y;
  for (int i = ty; i < 32; i += 8)
    tile[i][tx] = W[(size_t)(by + i) * N + (bx + tx)];
  __syncthreads();
  for (int i = ty; i < 32; i += 8)
    WT[(size_t)(bx + i) * K + (by + tx)] = __float2bfloat16(tile[tx][i]);
}

// ---------------- V transpose: Vt[b][g][d][perm(t)] = kv[b][t][512 + g*128 + d] --------
// perm swaps bits 2<->3 of t within each 16-group (see attn_k P layout).
__global__ __launch_bounds__(256) void vtrans_k(const __hip_bfloat16* __restrict__ kv,
                                                __hip_bfloat16* __restrict__ vt) {
  __shared__ __hip_bfloat16 tile[32][33];
  int bg = blockIdx.z;            // b*4+g
  int d0 = blockIdx.y * 32;
  int t0 = blockIdx.x * 32;
  int tx = threadIdx.x, ty = threadIdx.y;
  int b = bg >> 2, g = bg & 3;
  const __hip_bfloat16* src = kv + (size_t)b * T_ * KVD_ + 512 + g * HD_;
  for (int i = ty; i < 32; i += 8)
    tile[i][tx] = src[(size_t)(t0 + i) * KVD_ + d0 + tx];
  __syncthreads();
  __hip_bfloat16* dst = vt + (size_t)bg * HD_ * T_;
  int txp = (tx & ~12) | ((tx & 4) << 1) | ((tx & 8) >> 1);  // swap bits 2,3
  for (int i = ty; i < 32; i += 8)
    dst[(size_t)(d0 + i) * T_ + t0 + txp] = tile[tx][i];
}

// ---------------- row l2norm (in place, bf16), scale folded via `extra` ----------------
template<int PER>
__global__ __launch_bounds__(256) void rownorm_k(__hip_bfloat16* __restrict__ buf,
                                                 int stride, float extra) {
  const int tid = threadIdx.x;
  __hip_bfloat16* p = buf + (size_t)blockIdx.x * stride;
  float v[PER];
  float ss = 0.f;
  #pragma unroll
  for (int e = 0; e < PER; ++e) { v[e] = bf2f(p[tid + e * 256]); ss += v[e] * v[e]; }
  #pragma unroll
  for (int off = 32; off >= 1; off >>= 1) ss += __shfl_xor(ss, off, 64);
  __shared__ float wsum[4];
  if ((tid & 63) == 0) wsum[tid >> 6] = ss;
  __syncthreads();
  float tot = wsum[0] + wsum[1] + wsum[2] + wsum[3];
  float sc = extra / (sqrtf(tot) + 1e-12f);
  #pragma unroll
  for (int e = 0; e < PER; ++e) p[tid + e * 256] = __float2bfloat16(v[e] * sc);
}

// ---------------- GEMM v2: ring-3 LDS, counted-vmcnt pipeline (unchanged from R5) ------
template<typename OutT>
__global__ __launch_bounds__(512, 2) void gemm3_k(const __hip_bfloat16* __restrict__ A,
                                                  const __hip_bfloat16* __restrict__ BT,
                                                  OutT* __restrict__ Cc,
                                                  int M, int N, int K) {
  __shared__ alignas(16) __hip_bfloat16 As[3][128 * 64];
  __shared__ alignas(16) __hip_bfloat16 Bs[3][256 * 64];
  const int tid  = threadIdx.x;
  const int bm   = blockIdx.y * 128;
  const int bn   = blockIdx.x * 256;
  const int wave = tid >> 6, lane = tid & 63;
  const int wm = wave >> 2, wn = wave & 3;
  const int lm = lane & 15, quad = lane >> 4;
  const size_t Kz = (size_t)K;
  const int NT = K >> 6;

  const int srow = tid >> 3;                        // 0..63
  const int csw  = ((tid & 7) ^ (srow & 7)) * 8;    // swizzled 16B chunk offset
  const __hip_bfloat16* aSrc0 = A  + (size_t)(bm + srow) * Kz + csw;
  const __hip_bfloat16* aSrc1 = A  + (size_t)(bm + 64 + srow) * Kz + csw;
  const __hip_bfloat16* bSrc0 = BT + (size_t)(bn + srow) * Kz + csw;
  const __hip_bfloat16* bSrc1 = BT + (size_t)(bn + 64 + srow) * Kz + csw;
  const __hip_bfloat16* bSrc2 = BT + (size_t)(bn + 128 + srow) * Kz + csw;
  const __hip_bfloat16* bSrc3 = BT + (size_t)(bn + 192 + srow) * Kz + csw;

  auto stageA = [&](int slot, int koff) {
    async_copy16(aSrc0 + koff, As[slot] + tid * 8);
    async_copy16(aSrc1 + koff, As[slot] + (512 + tid) * 8);
  };
  auto stageB0 = [&](int slot, int koff) {
    async_copy16(bSrc0 + koff, Bs[slot] + tid * 8);
  };
  auto stageB123 = [&](int slot, int koff) {
    async_copy16(bSrc1 + koff, Bs[slot] + (512 + tid) * 8);
    async_copy16(bSrc2 + koff, Bs[slot] + (1024 + tid) * 8);
    async_copy16(bSrc3 + koff, Bs[slot] + (1536 + tid) * 8);
  };

  const int ch0 = ((quad) ^ (lm & 7)) * 8;
  const int ch1 = ((4 + quad) ^ (lm & 7)) * 8;
  const int arow = wm * 64 + lm;
  const int brow = wn * 64 + lm;

  f32x4 acc[4][4] = {};

  stageA(0, 0); stageB0(0, 0); stageB123(0, 0);
  if (NT > 1) { stageA(1, 64); stageB0(1, 64); stageB123(1, 64); }

  int s = 0;
  for (int t = 0; t < NT; ++t) {
    const int sn = (s + 2 > 2) ? (s - 1) : (s + 2);   // (s+2)%3
    const bool pre = (t + 2) < NT;
    const int koff = (t + 2) * 64;
    if (t + 1 < NT) asm volatile("s_waitcnt vmcnt(6)" ::: "memory");
    else            asm volatile("s_waitcnt vmcnt(0)" ::: "memory");
    __builtin_amdgcn_s_barrier();
    bf16x8 af[4][2], bf0[2][2];
    #pragma unroll
    for (int mf = 0; mf < 4; ++mf) {
      af[mf][0] = *(const bf16x8*)(As[s] + (arow + mf * 16) * 64 + ch0);
      af[mf][1] = *(const bf16x8*)(As[s] + (arow + mf * 16) * 64 + ch1);
    }
    #pragma unroll
    for (int nf = 0; nf < 2; ++nf) {
      bf0[nf][0] = *(const bf16x8*)(Bs[s] + (brow + nf * 16) * 64 + ch0);
      bf0[nf][1] = *(const bf16x8*)(Bs[s] + (brow + nf * 16) * 64 + ch1);
    }
    if (pre) { stageA(sn, koff); stageB0(sn, koff); }
    __builtin_amdgcn_s_barrier();
    __builtin_amdgcn_s_setprio(1);
    #pragma unroll
    for (int mf = 0; mf < 4; ++mf)
      #pragma unroll
      for (int nf = 0; nf < 2; ++nf) {
        acc[mf][nf] = __builtin_amdgcn_mfma_f32_16x16x32_bf16(af[mf][0], bf0[nf][0], acc[mf][nf], 0, 0, 0);
        acc[mf][nf] = __builtin_amdgcn_mfma_f32_16x16x32_bf16(af[mf][1], bf0[nf][1], acc[mf][nf], 0, 0, 0);
      }
    __builtin_amdgcn_s_setprio(0);
    __builtin_amdgcn_s_barrier();
    bf16x8 bf1[2][2];
    #pragma unroll
    for (int nf = 0; nf < 2; ++nf) {
      bf1[nf][0] = *(const bf16x8*)(Bs[s] + (brow + (nf + 2) * 16) * 64 + ch0);
      bf1[nf][1] = *(const bf16x8*)(Bs[s] + (brow + (nf + 2) * 16) * 64 + ch1);
    }
    if (pre) stageB123(sn, koff);
    __builtin_amdgcn_s_barrier();
    __builtin_amdgcn_s_setprio(1);
    #pragma unroll
    for (int mf = 0; mf < 4; ++mf)
      #pragma unroll
      for (int nf = 0; nf < 2; ++nf) {
        acc[mf][nf + 2] = __builtin_amdgcn_mfma_f32_16x16x32_bf16(af[mf][0], bf1[nf][0], acc[mf][nf + 2], 0, 0, 0);
        acc[mf][nf + 2] = __builtin_amdgcn_mfma_f32_16x16x32_bf16(af[mf][1], bf1[nf][1], acc[mf][nf + 2], 0, 0, 0);
      }
    __builtin_amdgcn_s_setprio(0);
    s = (s == 2) ? 0 : s + 1;
  }

  const int r0 = quad * 4;
  #pragma unroll
  for (int mf = 0; mf < 4; ++mf)
    #pragma unroll
    for (int nf = 0; nf < 4; ++nf)
      #pragma unroll
      for (int r = 0; r < 4; ++r) {
        int gr = bm + wm * 64 + mf * 16 + r0 + r;
        int gc = bn + wn * 64 + nf * 16 + lm;
        float v = acc[mf][nf][r];
        if constexpr (__is_same(OutT, float))
          Cc[(size_t)gr * N + gc] = v;
        else
          Cc[(size_t)gr * N + gc] = __float2bfloat16(v);
      }
}

// ---------------- flash attention v8b: v8 structure, corrected launch bounds --------
// 256 threads (4 waves x 32 q-rows), swapped QK^T 32x32x16, P fully in-register via
// bit-2/3-swapped V layout, bounded scores. V is NOT staged in LDS (512KB panel is
// L2-resident, shared by 64 blocks); PV B-frags load direct from global. LDS = 32KB
// (K double-buffer only).
// LAUNCH BOUNDS (hard-won): on this toolchain __launch_bounds__(_, w) caps VGPRs at
// 256/w (w=2 -> 128 observed R4/R5; w=4 -> 64 observed R2/R7 => catastrophic spill).
// Live state ~125 VGPR => w=2 is the only safe setting. Runtime residency is then
// VGPR-limited at 4 waves/SIMD = 4 independent 4-wave blocks/CU (LDS would allow 5).
__global__ __launch_bounds__(256, 2) void attn_k(const __hip_bfloat16* __restrict__ q,
                                                 const __hip_bfloat16* __restrict__ kv,
                                                 const __hip_bfloat16* __restrict__ vt,
                                                 __hip_bfloat16* __restrict__ y) {
  const int qt = (int)gridDim.x - 1 - (int)blockIdx.x;  // heavy blocks first
  const int h  = blockIdx.y;
  const int b  = blockIdx.z;
  const int g  = h >> 2;
  const int tid = threadIdx.x;
  const int wave = tid >> 6, lane = tid & 63;
  const int l31 = lane & 31, hi = lane >> 5;
  const int qbase = qt * 128 + wave * 32;
  const int qmax = qbase + 31;
  const int ntiles = 2 * qt + 2;

  // K tiles XOR-swizzled in LDS: chunk (row,c) holds global chunk c^(row&15).
  __shared__ alignas(16) __hip_bfloat16 Ks[2][64 * 128];

  const __hip_bfloat16* kb = kv + (size_t)b * T_ * KVD_ + g * HD_;
  const __hip_bfloat16* vb = vt + (size_t)(b * 4 + g) * HD_ * T_;

  auto stage = [&](int buf, int jt) {
    const size_t j1 = (size_t)jt * 64;
    #pragma unroll
    for (int e = 0; e < 4; ++e) {
      int idx = tid + e * 256;
      int row = idx >> 4, c = idx & 15;
      async_copy16(kb + (j1 + row) * KVD_ + ((c ^ (row & 15)) * 8), Ks[buf] + idx * 8);
    }
  };

  stage(0, 0);

  // Q -> registers (one row per lane&31; hi half picks the 8-elem sub-chunk)
  const __hip_bfloat16* qrow = q + ((size_t)b * T_ + qbase + l31) * C_ + h * HD_;
  bf16x8 qf[8];
  #pragma unroll
  for (int kc = 0; kc < 8; ++kc)
    qf[kc] = *(const bf16x8*)(qrow + kc * 16 + hi * 8);

  // V row base pointers (global, bit-2/3-swapped layout from vtrans_k)
  const __hip_bfloat16* vrow[4];
  #pragma unroll
  for (int ct = 0; ct < 4; ++ct)
    vrow[ct] = vb + (size_t)(ct * 32 + l31) * T_;

  __syncthreads();  // tile 0 staged (barrier drains vmcnt)

  f32x16 o_acc[4] = {};
  float l_acc = 0.f;

  for (int it = 0; it < ntiles; ++it) {
    const int cur = it & 1;
    if (it + 1 < ntiles) stage(cur ^ 1, it + 1);
    const int j0 = it * 64;
    if (j0 <= qmax) {  // wave-uniform: skip fully-masked tiles
      // ---- S^T = K Q^T : acc layout col=lane&31=q-row, row=kv-local ----
      f32x16 st0 = {}, st1 = {};
      __builtin_amdgcn_s_setprio(1);
      #pragma unroll
      for (int kc = 0; kc < 8; ++kc) {
        const int cs0 = (((2 * kc + hi) ^ (l31 & 15)) * 8);
        bf16x8 k0 = *(const bf16x8*)(Ks[cur] + l31 * 128 + cs0);
        bf16x8 k1 = *(const bf16x8*)(Ks[cur] + (32 + l31) * 128 + cs0);
        st0 = __builtin_amdgcn_mfma_f32_32x32x16_bf16(k0, qf[kc], st0, 0, 0, 0);
        st1 = __builtin_amdgcn_mfma_f32_32x32x16_bf16(k1, qf[kc], st1, 0, 0, 0);
      }
      __builtin_amdgcn_s_setprio(0);
      // ---- P = exp(S) + causal mask; per-lane only (q row = lane&31) ----
      const int qd = qbase + l31 - j0;  // kv_local <= qd is unmasked
      if (j0 + 63 <= qbase) {           // tile fully unmasked: skip compares
        #pragma unroll
        for (int r = 0; r < 16; ++r) {
          float p0 = __expf(st0[r]);
          float p1 = __expf(st1[r]);
          st0[r] = p0; st1[r] = p1;
          l_acc += p0 + p1;
        }
      } else {
        #pragma unroll
        for (int r = 0; r < 16; ++r) {
          const int ofs = (r & 3) + 8 * (r >> 2) + 4 * hi;  // kv_local (kt=0)
          float p0 = (ofs <= qd) ? __expf(st0[r]) : 0.f;
          float p1 = (ofs + 32 <= qd) ? __expf(st1[r]) : 0.f;
          st0[r] = p0; st1[r] = p1;
          l_acc += p0 + p1;
        }
      }
      // ---- pack P -> bf16 words W[m][i]; m = kv-group (8 kv), i = word ----
      unsigned int W[8][2];
      #pragma unroll
      for (int q4 = 0; q4 < 4; ++q4) {
        W[q4][0]     = pkbf(st0[4 * q4 + 0], st0[4 * q4 + 1]);
        W[q4][1]     = pkbf(st0[4 * q4 + 2], st0[4 * q4 + 3]);
        W[4 + q4][0] = pkbf(st1[4 * q4 + 0], st1[4 * q4 + 1]);
        W[4 + q4][1] = pkbf(st1[4 * q4 + 2], st1[4 * q4 + 3]);
      }
      // ---- O += P V (V frags direct from global; kv axis permuted in both) ----
      __builtin_amdgcn_s_setprio(1);
      #pragma unroll
      for (int kc = 0; kc < 4; ++kc) {
        u32x4 pw;
        pw[0] = W[2 * kc][0]; pw[1] = W[2 * kc][1];
        pw[2] = W[2 * kc + 1][0]; pw[3] = W[2 * kc + 1][1];
        bf16x8 pf = __builtin_bit_cast(bf16x8, pw);
        const int vofs = j0 + (2 * kc + hi) * 8;
        #pragma unroll
        for (int ct = 0; ct < 4; ++ct) {
          bf16x8 vf = *(const bf16x8*)(vrow[ct] + vofs);
          o_acc[ct] = __builtin_amdgcn_mfma_f32_32x32x16_bf16(pf, vf, o_acc[ct], 0, 0, 0);
        }
      }
      __builtin_amdgcn_s_setprio(0);
    }
    __syncthreads();  // drains prefetch vmcnt + protects buffer swap
  }

  // ---- epilogue: finish row sums (other hi half), divide, store ----
  float lsum = l_acc + __shfl_xor(l_acc, 32, 64);
  __hip_bfloat16* yb = y + ((size_t)b * T_ + qbase) * C_ + h * HD_ + l31;
  #pragma unroll
  for (int ct = 0; ct < 4; ++ct)
    #pragma unroll
    for (int r = 0; r < 16; ++r) {
      int row = (r & 3) + 8 * (r >> 2) + 4 * hi;
      float linv = 1.0f / __shfl(lsum, row, 64);
      yb[(size_t)row * C_ + ct * 32] = __float2bfloat16(o_acc[ct][r] * linv);
    }
}

extern "C" void kernel_launch(void* const* d_in, const int* in_sizes, int n_in,
                              void* d_out, int out_size, void* d_ws, size_t ws_size,
                              hipStream_t stream) {
  (void)in_sizes; (void)n_in; (void)out_size; (void)ws_size;
  const float* x     = (const float*)d_in[0];
  const float* Wq    = (const float*)d_in[1];
  const float* Wkv   = (const float*)d_in[2];
  const float* Wproj = (const float*)d_in[3];
  char* ws = (char*)d_ws;
  __hip_bfloat16* xb     = (__hip_bfloat16*)(ws);               // 32 MB (reused as y)
  __hip_bfloat16* WqT    = (__hip_bfloat16*)(ws + 33554432);    //  8 MB
  __hip_bfloat16* WkvT   = (__hip_bfloat16*)(ws + 41943040);    //  4 MB
  __hip_bfloat16* WprojT = (__hip_bfloat16*)(ws + 46137344);    //  8 MB
  __hip_bfloat16* qn     = (__hip_bfloat16*)(ws + 54525952);    // 32 MB
  __hip_bfloat16* kvb    = (__hip_bfloat16*)(ws + 88080384);    // 16 MB
  __hip_bfloat16* y      = xb;                                  // alias: xb dead after kv-gemm
  __hip_bfloat16* vt     = (__hip_bfloat16*)d_out;              // 16 MB scratch in d_out
  float* out             = (float*)d_out;

  f32_to_bf16_k<<<16384, 256, 0, stream>>>(x, xb, 4194304);
  transpose_f32_bf16_k<<<dim3(64, 64), dim3(32, 8), 0, stream>>>(Wq, WqT, 2048, 2048);
  transpose_f32_bf16_k<<<dim3(32, 64), dim3(32, 8), 0, stream>>>(Wkv, WkvT, 2048, 1024);
  transpose_f32_bf16_k<<<dim3(64, 64), dim3(32, 8), 0, stream>>>(Wproj, WprojT, 2048, 2048);
  gemm3_k<__hip_bfloat16><<<dim3(8, 64), 512, 0, stream>>>(xb, WqT, qn, 8192, 2048, 2048);
  gemm3_k<__hip_bfloat16><<<dim3(4, 64), 512, 0, stream>>>(xb, WkvT, kvb, 8192, 1024, 2048);
  rownorm_k<8><<<8192, 256, 0, stream>>>(qn, 2048, 0.08838834764831845f);  // 1/sqrt(HD) folded
  rownorm_k<2><<<8192, 256, 0, stream>>>(kvb, 1024, 1.0f);
  vtrans_k<<<dim3(64, 4, 16), dim3(32, 8), 0, stream>>>(kvb, vt);
  attn_k<<<dim3(16, 16, 4), 256, 0, stream>>>(qn, kvb, vt, y);
  gemm3_k<float><<<dim3(8, 64), 512, 0, stream>>>(y, WprojT, out, 8192, 2048, 2048);
}

// Round 9
// 516.796 us; speedup vs baseline: 1.7893x; 1.2437x over previous
//
#include <hip/hip_runtime.h>
#include <hip/hip_bf16.h>
#include <math.h>

#define B_   4
#define T_   2048
#define C_   2048
#define NH_  16
#define HD_  128
#define KVD_ 1024

typedef __attribute__((ext_vector_type(4))) float f32x4;
typedef __attribute__((ext_vector_type(16))) float f32x16;
typedef __attribute__((ext_vector_type(8))) short bf16x8;
typedef __attribute__((ext_vector_type(4))) unsigned int u32x4;

__device__ __forceinline__ void async_copy16(const __hip_bfloat16* g, __hip_bfloat16* l) {
  __builtin_amdgcn_global_load_lds((const __attribute__((address_space(1))) void*)g,
                                   (__attribute__((address_space(3))) void*)l,
                                   16, 0, 0);
}

__device__ __forceinline__ float bf2f(__hip_bfloat16 h) { return __bfloat162float(h); }

// pack two f32 -> one dword of 2 bf16 (a in low half)
__device__ __forceinline__ unsigned int pkbf(float a, float b) {
  float2 f2; f2.x = a; f2.y = b;
  __hip_bfloat162 h2 = __float22bfloat162_rn(f2);
  return *reinterpret_cast<unsigned int*>(&h2);
}

// ---------------- f32 -> bf16 convert (x) ----------------
__global__ __launch_bounds__(256) void f32_to_bf16_k(const float* __restrict__ src,
                                                     __hip_bfloat16* __restrict__ dst, int n4) {
  int i = blockIdx.x * 256 + threadIdx.x;
  if (i >= n4) return;
  float4 f = ((const float4*)src)[i];
  __hip_bfloat16 o[4] = {__float2bfloat16(f.x), __float2bfloat16(f.y),
                         __float2bfloat16(f.z), __float2bfloat16(f.w)};
  *(uint2*)(dst + (size_t)i * 4) = *(uint2*)o;
}

// ---------------- transpose + convert: WT[n][k] = bf16(W[k][n]) ----------------
__global__ __launch_bounds__(256) void transpose_f32_bf16_k(const float* __restrict__ W,
                                                            __hip_bfloat16* __restrict__ WT,
                                                            int K, int N) {
  __shared__ float tile[32][33];
  int bx = blockIdx.x * 32;  // n
  int by = blockIdx.y * 32;  // k
  int tx = threadIdx.x, ty = threadIdx.y;
  for (int i = ty; i < 32; i += 8)
    tile[i][tx] = W[(size_t)(by + i) * N + (bx + tx)];
  __syncthreads();
  for (int i = ty; i < 32; i += 8)
    WT[(size_t)(bx + i) * K + (by + tx)] = __float2bfloat16(tile[tx][i]);
}

// ---------------- V transpose: Vt[b][g][d][perm(t)] = kv[b][t][512 + g*128 + d] --------
// perm swaps bits 2<->3 of t within each 16-group (see attn_k P layout).
__global__ __launch_bounds__(256) void vtrans_k(const __hip_bfloat16* __restrict__ kv,
                                                __hip_bfloat16* __restrict__ vt) {
  __shared__ __hip_bfloat16 tile[32][33];
  int bg = blockIdx.z;            // b*4+g
  int d0 = blockIdx.y * 32;
  int t0 = blockIdx.x * 32;
  int tx = threadIdx.x, ty = threadIdx.y;
  int b = bg >> 2, g = bg & 3;
  const __hip_bfloat16* src = kv + (size_t)b * T_ * KVD_ + 512 + g * HD_;
  for (int i = ty; i < 32; i += 8)
    tile[i][tx] = src[(size_t)(t0 + i) * KVD_ + d0 + tx];
  __syncthreads();
  __hip_bfloat16* dst = vt + (size_t)bg * HD_ * T_;
  int txp = (tx & ~12) | ((tx & 4) << 1) | ((tx & 8) >> 1);  // swap bits 2,3
  for (int i = ty; i < 32; i += 8)
    dst[(size_t)(d0 + i) * T_ + t0 + txp] = tile[tx][i];
}

// ---------------- row l2norm (in place, bf16), scale folded via `extra` ----------------
template<int PER>
__global__ __launch_bounds__(256) void rownorm_k(__hip_bfloat16* __restrict__ buf,
                                                 int stride, float extra) {
  const int tid = threadIdx.x;
  __hip_bfloat16* p = buf + (size_t)blockIdx.x * stride;
  float v[PER];
  float ss = 0.f;
  #pragma unroll
  for (int e = 0; e < PER; ++e) { v[e] = bf2f(p[tid + e * 256]); ss += v[e] * v[e]; }
  #pragma unroll
  for (int off = 32; off >= 1; off >>= 1) ss += __shfl_xor(ss, off, 64);
  __shared__ float wsum[4];
  if ((tid & 63) == 0) wsum[tid >> 6] = ss;
  __syncthreads();
  float tot = wsum[0] + wsum[1] + wsum[2] + wsum[3];
  float sc = extra / (sqrtf(tot) + 1e-12f);
  #pragma unroll
  for (int e = 0; e < PER; ++e) p[tid + e * 256] = __float2bfloat16(v[e] * sc);
}

// ---------------- GEMM v3: 256x256 tile, BK=64, 4-phase counted-vmcnt pipeline --------
// C[M][N] = A[M][K] @ BT[N][K]^T. 512 threads = 8 waves (2M x 4N), wave output 128x64
// (acc 8x4 f32x4 = 128 VGPR). LDS 128KB: double-buffered 256x64 A + 256x64 B tiles.
// Per K-tile, 4 phases of 16 MFMA each:
//   P0: issue 4 stage-quarters(t+1); vmcnt(4) [= prev tile's 8 loads done, new 4 fly];
//       barrier; read af[m0-3] + bfA[n0-1]; MFMA m0-3 x n0-1; barrier
//   P1: issue remaining 4 stage-quarters(t+1); read bfB[n2-3]; MFMA m0-3 x n2-3; barrier
//   P2: read af[m4-7] (overwrite); MFMA m4-7 x n0-1; barrier
//   P3: MFMA m4-7 x n2-3; barrier
// vmcnt is COUNTED (never 0 mid-loop): loads issued in P0/P1 stay in flight across all
// barriers (raw s_barrier, no implicit drain). XOR chunk swizzle (c ^ row&7) on both
// stage-source and ds_read (same proven scheme as before). __launch_bounds__(512,1):
// VGPR cap 256 (live ~210); 1 block/CU (LDS-bound), 8 waves = 2 waves/SIMD -- the
// phase-pipeline operating point, latency hidden by the schedule not TLP.
template<typename OutT>
__global__ __launch_bounds__(512, 1) void gemm8_k(const __hip_bfloat16* __restrict__ A,
                                                  const __hip_bfloat16* __restrict__ BT,
                                                  OutT* __restrict__ Cc,
                                                  int M, int N, int K) {
  __shared__ alignas(16) __hip_bfloat16 As[2][256 * 64];
  __shared__ alignas(16) __hip_bfloat16 Bs[2][256 * 64];
  const int tid  = threadIdx.x;
  const int bm   = blockIdx.y * 256;
  const int bn   = blockIdx.x * 256;
  const int wave = tid >> 6, lane = tid & 63;
  const int wm = wave >> 2, wn = wave & 3;     // 2 x 4 wave grid
  const int lm = lane & 15, quad = lane >> 4;
  const size_t Kz = (size_t)K;
  const int NT = K >> 6;

  // staging: quarter p covers 64 rows; thread -> row (tid>>3), chunk (tid&7),
  // source chunk pre-swizzled (c ^ row&7); LDS dest linear at tid*16B.
  const int srow = tid >> 3;
  const int csw  = ((tid & 7) ^ (srow & 7)) * 8;
  const __hip_bfloat16* aQ[4];
  const __hip_bfloat16* bQ[4];
  #pragma unroll
  for (int p = 0; p < 4; ++p) {
    aQ[p] = A  + (size_t)(bm + p * 64 + srow) * Kz + csw;
    bQ[p] = BT + (size_t)(bn + p * 64 + srow) * Kz + csw;
  }
  auto stageA2 = [&](int buf, int p0, int koff) {   // A quarters p0, p0+1
    async_copy16(aQ[p0] + koff,     As[buf] + (p0) * 4096 + tid * 8);
    async_copy16(aQ[p0 + 1] + koff, As[buf] + (p0 + 1) * 4096 + tid * 8);
  };
  auto stageB2 = [&](int buf, int p0, int koff) {   // B quarters p0, p0+1
    async_copy16(bQ[p0] + koff,     Bs[buf] + (p0) * 4096 + tid * 8);
    async_copy16(bQ[p0 + 1] + koff, Bs[buf] + (p0 + 1) * 4096 + tid * 8);
  };

  // ds_read chunk offsets (elements): chunk (kk*4+quad) ^ (row&7); row&7 == lm&7
  const int ch0 = ((quad) ^ (lm & 7)) * 8;
  const int ch1 = ((4 + quad) ^ (lm & 7)) * 8;
  const int arow = wm * 128 + lm;   // + mf*16
  const int brow = wn * 64 + lm;    // + nf*16

  f32x4 acc[8][4] = {};

  // prologue: stage tile 0 fully (8 loads/thread)
  stageA2(0, 0, 0); stageA2(0, 2, 0); stageB2(0, 0, 0); stageB2(0, 2, 0);

  int cur = 0;
  for (int t = 0; t < NT; ++t) {
    const int nb = cur ^ 1;
    const bool pre = (t + 1) < NT;
    const int koff = (t + 1) * 64;

    // ---- P0 ----
    if (pre) { stageA2(nb, 0, koff); stageB2(nb, 0, koff); }
    if (pre) asm volatile("s_waitcnt vmcnt(4)" ::: "memory");
    else     asm volatile("s_waitcnt vmcnt(0)" ::: "memory");
    __builtin_amdgcn_s_barrier();   // all waves' tile-t loads landed
    bf16x8 af[4][2], bfA[2][2], bfB[2][2];
    #pragma unroll
    for (int mf = 0; mf < 4; ++mf) {
      af[mf][0] = *(const bf16x8*)(As[cur] + (arow + mf * 16) * 64 + ch0);
      af[mf][1] = *(const bf16x8*)(As[cur] + (arow + mf * 16) * 64 + ch1);
    }
    #pragma unroll
    for (int nf = 0; nf < 2; ++nf) {
      bfA[nf][0] = *(const bf16x8*)(Bs[cur] + (brow + nf * 16) * 64 + ch0);
      bfA[nf][1] = *(const bf16x8*)(Bs[cur] + (brow + nf * 16) * 64 + ch1);
    }
    __builtin_amdgcn_s_setprio(1);
    #pragma unroll
    for (int mf = 0; mf < 4; ++mf)
      #pragma unroll
      for (int nf = 0; nf < 2; ++nf) {
        acc[mf][nf] = __builtin_amdgcn_mfma_f32_16x16x32_bf16(af[mf][0], bfA[nf][0], acc[mf][nf], 0, 0, 0);
        acc[mf][nf] = __builtin_amdgcn_mfma_f32_16x16x32_bf16(af[mf][1], bfA[nf][1], acc[mf][nf], 0, 0, 0);
      }
    __builtin_amdgcn_s_setprio(0);
    __builtin_amdgcn_s_barrier();

    // ---- P1 ----
    if (pre) { stageA2(nb, 2, koff); stageB2(nb, 2, koff); }
    #pragma unroll
    for (int nf = 0; nf < 2; ++nf) {
      bfB[nf][0] = *(const bf16x8*)(Bs[cur] + (brow + (nf + 2) * 16) * 64 + ch0);
      bfB[nf][1] = *(const bf16x8*)(Bs[cur] + (brow + (nf + 2) * 16) * 64 + ch1);
    }
    __builtin_amdgcn_s_setprio(1);
    #pragma unroll
    for (int mf = 0; mf < 4; ++mf)
      #pragma unroll
      for (int nf = 0; nf < 2; ++nf) {
        acc[mf][nf + 2] = __builtin_amdgcn_mfma_f32_16x16x32_bf16(af[mf][0], bfB[nf][0], acc[mf][nf + 2], 0, 0, 0);
        acc[mf][nf + 2] = __builtin_amdgcn_mfma_f32_16x16x32_bf16(af[mf][1], bfB[nf][1], acc[mf][nf + 2], 0, 0, 0);
      }
    __builtin_amdgcn_s_setprio(0);
    __builtin_amdgcn_s_barrier();

    // ---- P2 ----
    #pragma unroll
    for (int mf = 0; mf < 4; ++mf) {
      af[mf][0] = *(const bf16x8*)(As[cur] + (arow + (mf + 4) * 16) * 64 + ch0);
      af[mf][1] = *(const bf16x8*)(As[cur] + (arow + (mf + 4) * 16) * 64 + ch1);
    }
    __builtin_amdgcn_s_setprio(1);
    #pragma unroll
    for (int mf = 0; mf < 4; ++mf)
      #pragma unroll
      for (int nf = 0; nf < 2; ++nf) {
        acc[mf + 4][nf] = __builtin_amdgcn_mfma_f32_16x16x32_bf16(af[mf][0], bfA[nf][0], acc[mf + 4][nf], 0, 0, 0);
        acc[mf + 4][nf] = __builtin_amdgcn_mfma_f32_16x16x32_bf16(af[mf][1], bfA[nf][1], acc[mf + 4][nf], 0, 0, 0);
      }
    __builtin_amdgcn_s_setprio(0);
    __builtin_amdgcn_s_barrier();

    // ---- P3 ----
    __builtin_amdgcn_s_setprio(1);
    #pragma unroll
    for (int mf = 0; mf < 4; ++mf)
      #pragma unroll
      for (int nf = 0; nf < 2; ++nf) {
        acc[mf + 4][nf + 2] = __builtin_amdgcn_mfma_f32_16x16x32_bf16(af[mf][0], bfB[nf][0], acc[mf + 4][nf + 2], 0, 0, 0);
        acc[mf + 4][nf + 2] = __builtin_amdgcn_mfma_f32_16x16x32_bf16(af[mf][1], bfB[nf][1], acc[mf + 4][nf + 2], 0, 0, 0);
      }
    __builtin_amdgcn_s_setprio(0);
    __builtin_amdgcn_s_barrier();

    cur = nb;
  }

  // epilogue (same frag->row/col mapping as proven kernels)
  const int r0 = quad * 4;
  #pragma unroll
  for (int mf = 0; mf < 8; ++mf)
    #pragma unroll
    for (int nf = 0; nf < 4; ++nf)
      #pragma unroll
      for (int r = 0; r < 4; ++r) {
        int gr = bm + wm * 128 + mf * 16 + r0 + r;
        int gc = bn + wn * 64 + nf * 16 + lm;
        float v = acc[mf][nf][r];
        if constexpr (__is_same(OutT, float))
          Cc[(size_t)gr * N + gc] = v;
        else
          Cc[(size_t)gr * N + gc] = __float2bfloat16(v);
      }
}

// ---------------- flash attention v6 (EXACT R5 revert): triangle-folded ----------------
// 256-thread blocks (4 waves x 32 q-rows, Q-tile 128), 120 VGPR, 64KB LDS, 2 blocks/CU.
// Block processes q-tile PAIR {15-p, p}: uniform 36 K-tiles/block, 512 blocks.
// Swapped QK^T (32x32x16), P fully in-register via bit-2/3-swapped V layout, V staged
// in LDS (R8 proved V-from-global is 3x worse: gathers serialize on the PV path).
__global__ __launch_bounds__(256, 2) void attn_k(const __hip_bfloat16* __restrict__ q,
                                                 const __hip_bfloat16* __restrict__ kv,
                                                 const __hip_bfloat16* __restrict__ vt,
                                                 __hip_bfloat16* __restrict__ y) {
  const int pp = blockIdx.x;      // pair index 0..7
  const int h  = blockIdx.y;
  const int b  = blockIdx.z;
  const int g  = h >> 2;
  const int tid = threadIdx.x;
  const int wave = tid >> 6, lane = tid & 63;
  const int l31 = lane & 31, hi = lane >> 5;

  __shared__ alignas(16) __hip_bfloat16 Ks[2][64 * 128];
  __shared__ alignas(16) __hip_bfloat16 Vts[2][128 * 64];

  const __hip_bfloat16* kb = kv + (size_t)b * T_ * KVD_ + g * HD_;
  const __hip_bfloat16* vb = vt + (size_t)(b * 4 + g) * HD_ * T_;

  auto stage = [&](int buf, int jt) {
    const size_t j1 = (size_t)jt * 64;
    #pragma unroll
    for (int e = 0; e < 4; ++e) {
      int idx = tid + e * 256;
      int row = idx >> 4, c = idx & 15;
      async_copy16(kb + (j1 + row) * KVD_ + ((c ^ (row & 15)) * 8), Ks[buf] + idx * 8);
    }
    #pragma unroll
    for (int e = 0; e < 4; ++e) {
      int idx = tid + e * 256;
      int row = idx >> 3, c = idx & 7;
      async_copy16(vb + (size_t)row * T_ + j1 + ((c ^ (row & 7)) * 8), Vts[buf] + idx * 8);
    }
  };

  stage(0, 0);  // first tile of first segment

  #pragma unroll
  for (int seg = 0; seg < 2; ++seg) {
    const int qt = seg ? pp : (15 - pp);
    const int qbase = qt * 128 + wave * 32;
    const int qmax = qbase + 31;
    const int ntiles = 2 * qt + 2;

    const __hip_bfloat16* qrow = q + ((size_t)b * T_ + qbase + l31) * C_ + h * HD_;
    bf16x8 qf[8];
    #pragma unroll
    for (int kc = 0; kc < 8; ++kc)
      qf[kc] = *(const bf16x8*)(qrow + kc * 16 + hi * 8);

    __syncthreads();  // tile 0 of this segment staged (barrier drains vmcnt)

    f32x16 o_acc[4] = {};
    float l_acc = 0.f;

    for (int it = 0; it < ntiles; ++it) {
      const int cur = it & 1;
      if (it + 1 < ntiles) stage(cur ^ 1, it + 1);
      const int j0 = it * 64;
      if (j0 <= qmax) {
        f32x16 st0 = {}, st1 = {};
        __builtin_amdgcn_s_setprio(1);
        #pragma unroll
        for (int kc = 0; kc < 8; ++kc) {
          const int cs0 = (((2 * kc + hi) ^ (l31 & 15)) * 8);
          bf16x8 k0 = *(const bf16x8*)(Ks[cur] + l31 * 128 + cs0);
          bf16x8 k1 = *(const bf16x8*)(Ks[cur] + (32 + l31) * 128 + cs0);
          st0 = __builtin_amdgcn_mfma_f32_32x32x16_bf16(k0, qf[kc], st0, 0, 0, 0);
          st1 = __builtin_amdgcn_mfma_f32_32x32x16_bf16(k1, qf[kc], st1, 0, 0, 0);
        }
        __builtin_amdgcn_s_setprio(0);
        const int qd = qbase + l31 - j0;
        if (j0 + 63 <= qbase) {
          #pragma unroll
          for (int r = 0; r < 16; ++r) {
            float p0 = __expf(st0[r]);
            float p1 = __expf(st1[r]);
            st0[r] = p0; st1[r] = p1;
            l_acc += p0 + p1;
          }
        } else {
          #pragma unroll
          for (int r = 0; r < 16; ++r) {
            const int ofs = (r & 3) + 8 * (r >> 2) + 4 * hi;
            float p0 = (ofs <= qd) ? __expf(st0[r]) : 0.f;
            float p1 = (ofs + 32 <= qd) ? __expf(st1[r]) : 0.f;
            st0[r] = p0; st1[r] = p1;
            l_acc += p0 + p1;
          }
        }
        unsigned int W[8][2];
        #pragma unroll
        for (int q4 = 0; q4 < 4; ++q4) {
          W[q4][0]     = pkbf(st0[4 * q4 + 0], st0[4 * q4 + 1]);
          W[q4][1]     = pkbf(st0[4 * q4 + 2], st0[4 * q4 + 3]);
          W[4 + q4][0] = pkbf(st1[4 * q4 + 0], st1[4 * q4 + 1]);
          W[4 + q4][1] = pkbf(st1[4 * q4 + 2], st1[4 * q4 + 3]);
        }
        __builtin_amdgcn_s_setprio(1);
        #pragma unroll
        for (int kc = 0; kc < 4; ++kc) {
          u32x4 pw;
          pw[0] = W[2 * kc][0]; pw[1] = W[2 * kc][1];
          pw[2] = W[2 * kc + 1][0]; pw[3] = W[2 * kc + 1][1];
          bf16x8 pf = __builtin_bit_cast(bf16x8, pw);
          const int csv = (((2 * kc + hi) ^ (l31 & 7)) * 8);
          #pragma unroll
          for (int ct = 0; ct < 4; ++ct) {
            bf16x8 vf = *(const bf16x8*)(Vts[cur] + (ct * 32 + l31) * 64 + csv);
            o_acc[ct] = __builtin_amdgcn_mfma_f32_32x32x16_bf16(pf, vf, o_acc[ct], 0, 0, 0);
          }
        }
        __builtin_amdgcn_s_setprio(0);
      }
      __syncthreads();
    }

    if (seg == 0) stage(0, 0);

    float lsum = l_acc + __shfl_xor(l_acc, 32, 64);
    float oinv[16];
    #pragma unroll
    for (int r = 0; r < 16; ++r) {
      int row = (r & 3) + 8 * (r >> 2) + 4 * hi;
      oinv[r] = 1.0f / __shfl(lsum, row, 64);
    }
    __hip_bfloat16* yb = y + ((size_t)b * T_ + qbase) * C_ + h * HD_ + l31;
    #pragma unroll
    for (int ct = 0; ct < 4; ++ct)
      #pragma unroll
      for (int r = 0; r < 16; ++r) {
        int row = (r & 3) + 8 * (r >> 2) + 4 * hi;
        yb[(size_t)row * C_ + ct * 32] = __float2bfloat16(o_acc[ct][r] * oinv[r]);
      }
  }
}

extern "C" void kernel_launch(void* const* d_in, const int* in_sizes, int n_in,
                              void* d_out, int out_size, void* d_ws, size_t ws_size,
                              hipStream_t stream) {
  (void)in_sizes; (void)n_in; (void)out_size; (void)ws_size;
  const float* x     = (const float*)d_in[0];
  const float* Wq    = (const float*)d_in[1];
  const float* Wkv   = (const float*)d_in[2];
  const float* Wproj = (const float*)d_in[3];
  char* ws = (char*)d_ws;
  __hip_bfloat16* xb     = (__hip_bfloat16*)(ws);               // 32 MB (reused as y)
  __hip_bfloat16* WqT    = (__hip_bfloat16*)(ws + 33554432);    //  8 MB
  __hip_bfloat16* WkvT   = (__hip_bfloat16*)(ws + 41943040);    //  4 MB
  __hip_bfloat16* WprojT = (__hip_bfloat16*)(ws + 46137344);    //  8 MB
  __hip_bfloat16* qn     = (__hip_bfloat16*)(ws + 54525952);    // 32 MB
  __hip_bfloat16* kvb    = (__hip_bfloat16*)(ws + 88080384);    // 16 MB
  __hip_bfloat16* y      = xb;                                  // alias: xb dead after kv-gemm
  __hip_bfloat16* vt     = (__hip_bfloat16*)d_out;              // 16 MB scratch in d_out
  float* out             = (float*)d_out;

  f32_to_bf16_k<<<16384, 256, 0, stream>>>(x, xb, 4194304);
  transpose_f32_bf16_k<<<dim3(64, 64), dim3(32, 8), 0, stream>>>(Wq, WqT, 2048, 2048);
  transpose_f32_bf16_k<<<dim3(32, 64), dim3(32, 8), 0, stream>>>(Wkv, WkvT, 2048, 1024);
  transpose_f32_bf16_k<<<dim3(64, 64), dim3(32, 8), 0, stream>>>(Wproj, WprojT, 2048, 2048);
  gemm8_k<__hip_bfloat16><<<dim3(8, 32), 512, 0, stream>>>(xb, WqT, qn, 8192, 2048, 2048);
  gemm8_k<__hip_bfloat16><<<dim3(4, 32), 512, 0, stream>>>(xb, WkvT, kvb, 8192, 1024, 2048);
  rownorm_k<8><<<8192, 256, 0, stream>>>(qn, 2048, 0.08838834764831845f);  // 1/sqrt(HD) folded
  rownorm_k<2><<<8192, 256, 0, stream>>>(kvb, 1024, 1.0f);
  vtrans_k<<<dim3(64, 4, 16), dim3(32, 8), 0, stream>>>(kvb, vt);
  attn_k<<<dim3(8, 16, 4), 256, 0, stream>>>(qn, kvb, vt, y);
  gemm8_k<float><<<dim3(8, 32), 512, 0, stream>>>(y, WprojT, out, 8192, 2048, 2048);
}

// Round 10
// 506.013 us; speedup vs baseline: 1.8274x; 1.0213x over previous
//
#include <hip/hip_runtime.h>
#include <hip/hip_bf16.h>
#include <math.h>

#define B_   4
#define T_   2048
#define C_   2048
#define NH_  16
#define HD_  128
#define KVD_ 1024

typedef __attribute__((ext_vector_type(4))) float f32x4;
typedef __attribute__((ext_vector_type(16))) float f32x16;
typedef __attribute__((ext_vector_type(8))) short bf16x8;
typedef __attribute__((ext_vector_type(4))) unsigned int u32x4;

__device__ __forceinline__ void async_copy16(const __hip_bfloat16* g, __hip_bfloat16* l) {
  __builtin_amdgcn_global_load_lds((const __attribute__((address_space(1))) void*)g,
                                   (__attribute__((address_space(3))) void*)l,
                                   16, 0, 0);
}

__device__ __forceinline__ float bf2f(__hip_bfloat16 h) { return __bfloat162float(h); }

// pack two f32 -> one dword of 2 bf16 (a in low half)
__device__ __forceinline__ unsigned int pkbf(float a, float b) {
  float2 f2; f2.x = a; f2.y = b;
  __hip_bfloat162 h2 = __float22bfloat162_rn(f2);
  return *reinterpret_cast<unsigned int*>(&h2);
}

// ---------------- f32 -> bf16 convert (x) ----------------
__global__ __launch_bounds__(256) void f32_to_bf16_k(const float* __restrict__ src,
                                                     __hip_bfloat16* __restrict__ dst, int n4) {
  int i = blockIdx.x * 256 + threadIdx.x;
  if (i >= n4) return;
  float4 f = ((const float4*)src)[i];
  __hip_bfloat16 o[4] = {__float2bfloat16(f.x), __float2bfloat16(f.y),
                         __float2bfloat16(f.z), __float2bfloat16(f.w)};
  *(uint2*)(dst + (size_t)i * 4) = *(uint2*)o;
}

// ---------------- transpose + convert: WT[n][k] = bf16(W[k][n]) ----------------
__global__ __launch_bounds__(256) void transpose_f32_bf16_k(const float* __restrict__ W,
                                                            __hip_bfloat16* __restrict__ WT,
                                                            int K, int N) {
  __shared__ float tile[32][33];
  int bx = blockIdx.x * 32;  // n
  int by = blockIdx.y * 32;  // k
  int tx = threadIdx.x, ty = threadIdx.y;
  for (int i = ty; i < 32; i += 8)
    tile[i][tx] = W[(size_t)(by + i) * N + (bx + tx)];
  __syncthreads();
  for (int i = ty; i < 32; i += 8)
    WT[(size_t)(bx + i) * K + (by + tx)] = __float2bfloat16(tile[tx][i]);
}

// ---------------- V transpose: Vt[b][g][d][perm(t)] = kv[b][t][512 + g*128 + d] --------
// perm swaps bits 2<->3 of t within each 16-group (see attn_k P layout).
__global__ __launch_bounds__(256) void vtrans_k(const __hip_bfloat16* __restrict__ kv,
                                                __hip_bfloat16* __restrict__ vt) {
  __shared__ __hip_bfloat16 tile[32][33];
  int bg = blockIdx.z;            // b*4+g
  int d0 = blockIdx.y * 32;
  int t0 = blockIdx.x * 32;
  int tx = threadIdx.x, ty = threadIdx.y;
  int b = bg >> 2, g = bg & 3;
  const __hip_bfloat16* src = kv + (size_t)b * T_ * KVD_ + 512 + g * HD_;
  for (int i = ty; i < 32; i += 8)
    tile[i][tx] = src[(size_t)(t0 + i) * KVD_ + d0 + tx];
  __syncthreads();
  __hip_bfloat16* dst = vt + (size_t)bg * HD_ * T_;
  int txp = (tx & ~12) | ((tx & 4) << 1) | ((tx & 8) >> 1);  // swap bits 2,3
  for (int i = ty; i < 32; i += 8)
    dst[(size_t)(d0 + i) * T_ + t0 + txp] = tile[tx][i];
}

// ---------------- row l2norm (in place, bf16), scale folded via `extra` ----------------
template<int PER>
__global__ __launch_bounds__(256) void rownorm_k(__hip_bfloat16* __restrict__ buf,
                                                 int stride, float extra) {
  const int tid = threadIdx.x;
  __hip_bfloat16* p = buf + (size_t)blockIdx.x * stride;
  float v[PER];
  float ss = 0.f;
  #pragma unroll
  for (int e = 0; e < PER; ++e) { v[e] = bf2f(p[tid + e * 256]); ss += v[e] * v[e]; }
  #pragma unroll
  for (int off = 32; off >= 1; off >>= 1) ss += __shfl_xor(ss, off, 64);
  __shared__ float wsum[4];
  if ((tid & 63) == 0) wsum[tid >> 6] = ss;
  __syncthreads();
  float tot = wsum[0] + wsum[1] + wsum[2] + wsum[3];
  float sc = extra / (sqrtf(tot) + 1e-12f);
  #pragma unroll
  for (int e = 0; e < PER; ++e) p[tid + e * 256] = __float2bfloat16(v[e] * sc);
}

// ---------------- GEMM v2 (EXACT R5 revert): ring-3 LDS, counted-vmcnt pipeline --------
// R9 lesson: the 256x256 4-phase variant (gemm8) was ~20% SLOWER -- coarse phase-split
// without fine interleave (m196 anti-pattern) + 1 block/CU. This ring-3 128x256 version
// is the proven best (R5: all three GEMMs < 110 us).
template<typename OutT>
__global__ __launch_bounds__(512, 2) void gemm3_k(const __hip_bfloat16* __restrict__ A,
                                                  const __hip_bfloat16* __restrict__ BT,
                                                  OutT* __restrict__ Cc,
                                                  int M, int N, int K) {
  __shared__ alignas(16) __hip_bfloat16 As[3][128 * 64];
  __shared__ alignas(16) __hip_bfloat16 Bs[3][256 * 64];
  const int tid  = threadIdx.x;
  const int bm   = blockIdx.y * 128;
  const int bn   = blockIdx.x * 256;
  const int wave = tid >> 6, lane = tid & 63;
  const int wm = wave >> 2, wn = wave & 3;
  const int lm = lane & 15, quad = lane >> 4;
  const size_t Kz = (size_t)K;
  const int NT = K >> 6;

  const int srow = tid >> 3;                        // 0..63
  const int csw  = ((tid & 7) ^ (srow & 7)) * 8;    // swizzled 16B chunk offset
  const __hip_bfloat16* aSrc0 = A  + (size_t)(bm + srow) * Kz + csw;
  const __hip_bfloat16* aSrc1 = A  + (size_t)(bm + 64 + srow) * Kz + csw;
  const __hip_bfloat16* bSrc0 = BT + (size_t)(bn + srow) * Kz + csw;
  const __hip_bfloat16* bSrc1 = BT + (size_t)(bn + 64 + srow) * Kz + csw;
  const __hip_bfloat16* bSrc2 = BT + (size_t)(bn + 128 + srow) * Kz + csw;
  const __hip_bfloat16* bSrc3 = BT + (size_t)(bn + 192 + srow) * Kz + csw;

  auto stageA = [&](int slot, int koff) {
    async_copy16(aSrc0 + koff, As[slot] + tid * 8);
    async_copy16(aSrc1 + koff, As[slot] + (512 + tid) * 8);
  };
  auto stageB0 = [&](int slot, int koff) {
    async_copy16(bSrc0 + koff, Bs[slot] + tid * 8);
  };
  auto stageB123 = [&](int slot, int koff) {
    async_copy16(bSrc1 + koff, Bs[slot] + (512 + tid) * 8);
    async_copy16(bSrc2 + koff, Bs[slot] + (1024 + tid) * 8);
    async_copy16(bSrc3 + koff, Bs[slot] + (1536 + tid) * 8);
  };

  const int ch0 = ((quad) ^ (lm & 7)) * 8;
  const int ch1 = ((4 + quad) ^ (lm & 7)) * 8;
  const int arow = wm * 64 + lm;
  const int brow = wn * 64 + lm;

  f32x4 acc[4][4] = {};

  stageA(0, 0); stageB0(0, 0); stageB123(0, 0);
  if (NT > 1) { stageA(1, 64); stageB0(1, 64); stageB123(1, 64); }

  int s = 0;
  for (int t = 0; t < NT; ++t) {
    const int sn = (s + 2 > 2) ? (s - 1) : (s + 2);   // (s+2)%3
    const bool pre = (t + 2) < NT;
    const int koff = (t + 2) * 64;
    if (t + 1 < NT) asm volatile("s_waitcnt vmcnt(6)" ::: "memory");
    else            asm volatile("s_waitcnt vmcnt(0)" ::: "memory");
    __builtin_amdgcn_s_barrier();
    bf16x8 af[4][2], bf0[2][2];
    #pragma unroll
    for (int mf = 0; mf < 4; ++mf) {
      af[mf][0] = *(const bf16x8*)(As[s] + (arow + mf * 16) * 64 + ch0);
      af[mf][1] = *(const bf16x8*)(As[s] + (arow + mf * 16) * 64 + ch1);
    }
    #pragma unroll
    for (int nf = 0; nf < 2; ++nf) {
      bf0[nf][0] = *(const bf16x8*)(Bs[s] + (brow + nf * 16) * 64 + ch0);
      bf0[nf][1] = *(const bf16x8*)(Bs[s] + (brow + nf * 16) * 64 + ch1);
    }
    if (pre) { stageA(sn, koff); stageB0(sn, koff); }
    __builtin_amdgcn_s_barrier();
    __builtin_amdgcn_s_setprio(1);
    #pragma unroll
    for (int mf = 0; mf < 4; ++mf)
      #pragma unroll
      for (int nf = 0; nf < 2; ++nf) {
        acc[mf][nf] = __builtin_amdgcn_mfma_f32_16x16x32_bf16(af[mf][0], bf0[nf][0], acc[mf][nf], 0, 0, 0);
        acc[mf][nf] = __builtin_amdgcn_mfma_f32_16x16x32_bf16(af[mf][1], bf0[nf][1], acc[mf][nf], 0, 0, 0);
      }
    __builtin_amdgcn_s_setprio(0);
    __builtin_amdgcn_s_barrier();
    bf16x8 bf1[2][2];
    #pragma unroll
    for (int nf = 0; nf < 2; ++nf) {
      bf1[nf][0] = *(const bf16x8*)(Bs[s] + (brow + (nf + 2) * 16) * 64 + ch0);
      bf1[nf][1] = *(const bf16x8*)(Bs[s] + (brow + (nf + 2) * 16) * 64 + ch1);
    }
    if (pre) stageB123(sn, koff);
    __builtin_amdgcn_s_barrier();
    __builtin_amdgcn_s_setprio(1);
    #pragma unroll
    for (int mf = 0; mf < 4; ++mf)
      #pragma unroll
      for (int nf = 0; nf < 2; ++nf) {
        acc[mf][nf + 2] = __builtin_amdgcn_mfma_f32_16x16x32_bf16(af[mf][0], bf1[nf][0], acc[mf][nf + 2], 0, 0, 0);
        acc[mf][nf + 2] = __builtin_amdgcn_mfma_f32_16x16x32_bf16(af[mf][1], bf1[nf][1], acc[mf][nf + 2], 0, 0, 0);
      }
    __builtin_amdgcn_s_setprio(0);
    s = (s == 2) ? 0 : s + 1;
  }

  const int r0 = quad * 4;
  #pragma unroll
  for (int mf = 0; mf < 4; ++mf)
    #pragma unroll
    for (int nf = 0; nf < 4; ++nf)
      #pragma unroll
      for (int r = 0; r < 4; ++r) {
        int gr = bm + wm * 64 + mf * 16 + r0 + r;
        int gc = bn + wn * 64 + nf * 16 + lm;
        float v = acc[mf][nf][r];
        if constexpr (__is_same(OutT, float))
          Cc[(size_t)gr * N + gc] = v;
        else
          Cc[(size_t)gr * N + gc] = __float2bfloat16(v);
      }
}

// ---------------- flash attention v9: single-V-buffer, 48KB LDS, 3 blocks/CU ----------
// v6 core (swapped QK^T 32x32x16, P in-register, V in LDS, bounded scores) with V
// SINGLE-buffered: V[t] is only read at PV[t], which follows the long QK^T+exp+pack
// phase -- so stage V[t] at iter start (4 loads FIRST), K[t+1] after (4 loads), compute
// QK^T (hides V latency), then counted `vmcnt(4)` (retires exactly the V loads, K stays
// in flight) + raw s_barrier (all waves' V quarters visible), then PV. End-of-iter
// __syncthreads protects the V overwrite (same drain point v6 had).
// LDS 64->48KB => 3 independent blocks/CU (12 waves/CU, 3/SIMD; VGPR 128 allows 4).
// Triangle unfolded (1024 blocks, heavy-first): 3-deep residency smooths imbalance.
__global__ __launch_bounds__(256, 2) void attn_k(const __hip_bfloat16* __restrict__ q,
                                                 const __hip_bfloat16* __restrict__ kv,
                                                 const __hip_bfloat16* __restrict__ vt,
                                                 __hip_bfloat16* __restrict__ y) {
  const int qt = (int)gridDim.x - 1 - (int)blockIdx.x;  // heavy blocks first
  const int h  = blockIdx.y;
  const int b  = blockIdx.z;
  const int g  = h >> 2;
  const int tid = threadIdx.x;
  const int wave = tid >> 6, lane = tid & 63;
  const int l31 = lane & 31, hi = lane >> 5;
  const int qbase = qt * 128 + wave * 32;
  const int qmax = qbase + 31;
  const int ntiles = 2 * qt + 2;

  // K double-buffered (32KB), V single (16KB). XOR-swizzled 16B chunks as before.
  __shared__ alignas(16) __hip_bfloat16 Ks[2][64 * 128];
  __shared__ alignas(16) __hip_bfloat16 Vts[128 * 64];

  const __hip_bfloat16* kb = kv + (size_t)b * T_ * KVD_ + g * HD_;
  const __hip_bfloat16* vb = vt + (size_t)(b * 4 + g) * HD_ * T_;

  auto stage_k = [&](int buf, int jt) {
    const size_t j1 = (size_t)jt * 64;
    #pragma unroll
    for (int e = 0; e < 4; ++e) {
      int idx = tid + e * 256;
      int row = idx >> 4, c = idx & 15;
      async_copy16(kb + (j1 + row) * KVD_ + ((c ^ (row & 15)) * 8), Ks[buf] + idx * 8);
    }
  };
  auto stage_v = [&](int jt) {
    const size_t j1 = (size_t)jt * 64;
    #pragma unroll
    for (int e = 0; e < 4; ++e) {
      int idx = tid + e * 256;
      int row = idx >> 3, c = idx & 7;
      async_copy16(vb + (size_t)row * T_ + j1 + ((c ^ (row & 7)) * 8), Vts + idx * 8);
    }
  };

  stage_k(0, 0);

  // Q -> registers (one row per lane&31; hi half picks the 8-elem sub-chunk)
  const __hip_bfloat16* qrow = q + ((size_t)b * T_ + qbase + l31) * C_ + h * HD_;
  bf16x8 qf[8];
  #pragma unroll
  for (int kc = 0; kc < 8; ++kc)
    qf[kc] = *(const bf16x8*)(qrow + kc * 16 + hi * 8);

  __syncthreads();  // K tile 0 staged (barrier drains vmcnt)

  f32x16 o_acc[4] = {};
  float l_acc = 0.f;

  for (int it = 0; it < ntiles; ++it) {
    const int cur = it & 1;
    // V for THIS tile first (vmcnt(4) below isolates these 4 loads), then K prefetch.
    stage_v(it);
    if (it + 1 < ntiles) stage_k(cur ^ 1, it + 1);
    const int j0 = it * 64;
    const bool act = (j0 <= qmax);  // wave-uniform
    unsigned int W[8][2];
    if (act) {
      // ---- S^T = K Q^T : acc layout col=lane&31=q-row, row=kv-local ----
      f32x16 st0 = {}, st1 = {};
      __builtin_amdgcn_s_setprio(1);
      #pragma unroll
      for (int kc = 0; kc < 8; ++kc) {
        const int cs0 = (((2 * kc + hi) ^ (l31 & 15)) * 8);
        bf16x8 k0 = *(const bf16x8*)(Ks[cur] + l31 * 128 + cs0);
        bf16x8 k1 = *(const bf16x8*)(Ks[cur] + (32 + l31) * 128 + cs0);
        st0 = __builtin_amdgcn_mfma_f32_32x32x16_bf16(k0, qf[kc], st0, 0, 0, 0);
        st1 = __builtin_amdgcn_mfma_f32_32x32x16_bf16(k1, qf[kc], st1, 0, 0, 0);
      }
      __builtin_amdgcn_s_setprio(0);
      // ---- P = exp(S) + causal mask; per-lane only (q row = lane&31) ----
      const int qd = qbase + l31 - j0;
      if (j0 + 63 <= qbase) {
        #pragma unroll
        for (int r = 0; r < 16; ++r) {
          float p0 = __expf(st0[r]);
          float p1 = __expf(st1[r]);
          st0[r] = p0; st1[r] = p1;
          l_acc += p0 + p1;
        }
      } else {
        #pragma unroll
        for (int r = 0; r < 16; ++r) {
          const int ofs = (r & 3) + 8 * (r >> 2) + 4 * hi;
          float p0 = (ofs <= qd) ? __expf(st0[r]) : 0.f;
          float p1 = (ofs + 32 <= qd) ? __expf(st1[r]) : 0.f;
          st0[r] = p0; st1[r] = p1;
          l_acc += p0 + p1;
        }
      }
      #pragma unroll
      for (int q4 = 0; q4 < 4; ++q4) {
        W[q4][0]     = pkbf(st0[4 * q4 + 0], st0[4 * q4 + 1]);
        W[q4][1]     = pkbf(st0[4 * q4 + 2], st0[4 * q4 + 3]);
        W[4 + q4][0] = pkbf(st1[4 * q4 + 0], st1[4 * q4 + 1]);
        W[4 + q4][1] = pkbf(st1[4 * q4 + 2], st1[4 * q4 + 3]);
      }
    }
    // V tile fully landed: each wave retires its own 4 V loads (K stays in flight),
    // then the barrier makes every wave's quarter visible to all.
    if (it + 1 < ntiles) asm volatile("s_waitcnt vmcnt(4)" ::: "memory");
    else                 asm volatile("s_waitcnt vmcnt(0)" ::: "memory");
    __builtin_amdgcn_s_barrier();
    if (act) {
      // ---- O += P V (kv axis permuted identically in P-frag and V storage) ----
      __builtin_amdgcn_s_setprio(1);
      #pragma unroll
      for (int kc = 0; kc < 4; ++kc) {
        u32x4 pw;
        pw[0] = W[2 * kc][0]; pw[1] = W[2 * kc][1];
        pw[2] = W[2 * kc + 1][0]; pw[3] = W[2 * kc + 1][1];
        bf16x8 pf = __builtin_bit_cast(bf16x8, pw);
        const int csv = (((2 * kc + hi) ^ (l31 & 7)) * 8);
        #pragma unroll
        for (int ct = 0; ct < 4; ++ct) {
          bf16x8 vf = *(const bf16x8*)(Vts + (ct * 32 + l31) * 64 + csv);
          o_acc[ct] = __builtin_amdgcn_mfma_f32_32x32x16_bf16(pf, vf, o_acc[ct], 0, 0, 0);
        }
      }
      __builtin_amdgcn_s_setprio(0);
    }
    __syncthreads();  // PV done in all waves before next V overwrite; drains K prefetch
  }

  // ---- epilogue: finish row sums (other hi half), divide, store ----
  float lsum = l_acc + __shfl_xor(l_acc, 32, 64);
  __hip_bfloat16* yb = y + ((size_t)b * T_ + qbase) * C_ + h * HD_ + l31;
  #pragma unroll
  for (int ct = 0; ct < 4; ++ct)
    #pragma unroll
    for (int r = 0; r < 16; ++r) {
      int row = (r & 3) + 8 * (r >> 2) + 4 * hi;
      float linv = 1.0f / __shfl(lsum, row, 64);
      yb[(size_t)row * C_ + ct * 32] = __float2bfloat16(o_acc[ct][r] * linv);
    }
}

extern "C" void kernel_launch(void* const* d_in, const int* in_sizes, int n_in,
                              void* d_out, int out_size, void* d_ws, size_t ws_size,
                              hipStream_t stream) {
  (void)in_sizes; (void)n_in; (void)out_size; (void)ws_size;
  const float* x     = (const float*)d_in[0];
  const float* Wq    = (const float*)d_in[1];
  const float* Wkv   = (const float*)d_in[2];
  const float* Wproj = (const float*)d_in[3];
  char* ws = (char*)d_ws;
  __hip_bfloat16* xb     = (__hip_bfloat16*)(ws);               // 32 MB (reused as y)
  __hip_bfloat16* WqT    = (__hip_bfloat16*)(ws + 33554432);    //  8 MB
  __hip_bfloat16* WkvT   = (__hip_bfloat16*)(ws + 41943040);    //  4 MB
  __hip_bfloat16* WprojT = (__hip_bfloat16*)(ws + 46137344);    //  8 MB
  __hip_bfloat16* qn     = (__hip_bfloat16*)(ws + 54525952);    // 32 MB
  __hip_bfloat16* kvb    = (__hip_bfloat16*)(ws + 88080384);    // 16 MB
  __hip_bfloat16* y      = xb;                                  // alias: xb dead after kv-gemm
  __hip_bfloat16* vt     = (__hip_bfloat16*)d_out;              // 16 MB scratch in d_out
  float* out             = (float*)d_out;

  f32_to_bf16_k<<<16384, 256, 0, stream>>>(x, xb, 4194304);
  transpose_f32_bf16_k<<<dim3(64, 64), dim3(32, 8), 0, stream>>>(Wq, WqT, 2048, 2048);
  transpose_f32_bf16_k<<<dim3(32, 64), dim3(32, 8), 0, stream>>>(Wkv, WkvT, 2048, 1024);
  transpose_f32_bf16_k<<<dim3(64, 64), dim3(32, 8), 0, stream>>>(Wproj, WprojT, 2048, 2048);
  gemm3_k<__hip_bfloat16><<<dim3(8, 64), 512, 0, stream>>>(xb, WqT, qn, 8192, 2048, 2048);
  gemm3_k<__hip_bfloat16><<<dim3(4, 64), 512, 0, stream>>>(xb, WkvT, kvb, 8192, 1024, 2048);
  rownorm_k<8><<<8192, 256, 0, stream>>>(qn, 2048, 0.08838834764831845f);  // 1/sqrt(HD) folded
  rownorm_k<2><<<8192, 256, 0, stream>>>(kvb, 1024, 1.0f);
  vtrans_k<<<dim3(64, 4, 16), dim3(32, 8), 0, stream>>>(kvb, vt);
  attn_k<<<dim3(16, 16, 4), 256, 0, stream>>>(qn, kvb, vt, y);
  gemm3_k<float><<<dim3(8, 64), 512, 0, stream>>>(y, WprojT, out, 8192, 2048, 2048);
}

// Round 11
// 464.846 us; speedup vs baseline: 1.9893x; 1.0886x over previous
//
#include <hip/hip_runtime.h>
#include <hip/hip_bf16.h>
#include <math.h>

#define B_   4
#define T_   2048
#define C_   2048
#define NH_  16
#define HD_  128
#define KVD_ 1024

typedef __attribute__((ext_vector_type(4))) float f32x4;
typedef __attribute__((ext_vector_type(16))) float f32x16;
typedef __attribute__((ext_vector_type(8))) short bf16x8;
typedef __attribute__((ext_vector_type(4))) unsigned int u32x4;

__device__ __forceinline__ void async_copy16(const __hip_bfloat16* g, __hip_bfloat16* l) {
  __builtin_amdgcn_global_load_lds((const __attribute__((address_space(1))) void*)g,
                                   (__attribute__((address_space(3))) void*)l,
                                   16, 0, 0);
}

__device__ __forceinline__ float bf2f(__hip_bfloat16 h) { return __bfloat162float(h); }

// pack two f32 -> one dword of 2 bf16 (a in low half), round-to-nearest
__device__ __forceinline__ unsigned int pkbf(float a, float b) {
  float2 f2; f2.x = a; f2.y = b;
  __hip_bfloat162 h2 = __float22bfloat162_rn(f2);
  return *reinterpret_cast<unsigned int*>(&h2);
}

// ---------------- f32 -> bf16 convert (x) ----------------
__global__ __launch_bounds__(256) void f32_to_bf16_k(const float* __restrict__ src,
                                                     __hip_bfloat16* __restrict__ dst, int n4) {
  int i = blockIdx.x * 256 + threadIdx.x;
  if (i >= n4) return;
  float4 f = ((const float4*)src)[i];
  __hip_bfloat16 o[4] = {__float2bfloat16(f.x), __float2bfloat16(f.y),
                         __float2bfloat16(f.z), __float2bfloat16(f.w)};
  *(uint2*)(dst + (size_t)i * 4) = *(uint2*)o;
}

// ---------------- transpose + convert: WT[n][k] = bf16(W[k][n]) ----------------
__global__ __launch_bounds__(256) void transpose_f32_bf16_k(const float* __restrict__ W,
                                                            __hip_bfloat16* __restrict__ WT,
                                                            int K, int N) {
  __shared__ float tile[32][33];
  int bx = blockIdx.x * 32;  // n
  int by = blockIdx.y * 32;  // k
  int tx = threadIdx.x, ty = threadIdx.y;
  for (int i = ty; i < 32; i += 8)
    tile[i][tx] = W[(size_t)(by + i) * N + (bx + tx)];
  __syncthreads();
  for (int i = ty; i < 32; i += 8)
    WT[(size_t)(bx + i) * K + (by + tx)] = __float2bfloat16(tile[tx][i]);
}

// ---------------- V transpose: Vt[b][g][d][perm(t)] = kv[b][t][512 + g*128 + d] --------
// perm swaps bits 2<->3 of t within each 16-group (see attn_k P layout).
__global__ __launch_bounds__(256) void vtrans_k(const __hip_bfloat16* __restrict__ kv,
                                                __hip_bfloat16* __restrict__ vt) {
  __shared__ __hip_bfloat16 tile[32][33];
  int bg = blockIdx.z;            // b*4+g
  int d0 = blockIdx.y * 32;
  int t0 = blockIdx.x * 32;
  int tx = threadIdx.x, ty = threadIdx.y;
  int b = bg >> 2, g = bg & 3;
  const __hip_bfloat16* src = kv + (size_t)b * T_ * KVD_ + 512 + g * HD_;
  for (int i = ty; i < 32; i += 8)
    tile[i][tx] = src[(size_t)(t0 + i) * KVD_ + d0 + tx];
  __syncthreads();
  __hip_bfloat16* dst = vt + (size_t)bg * HD_ * T_;
  int txp = (tx & ~12) | ((tx & 4) << 1) | ((tx & 8) >> 1);  // swap bits 2,3
  for (int i = ty; i < 32; i += 8)
    dst[(size_t)(d0 + i) * T_ + t0 + txp] = tile[tx][i];
}

// ---------------- row l2norm (in place, bf16), scale folded via `extra` ----------------
// Vectorized (G13): each thread owns PER CONTIGUOUS bf16 (16B for PER=8, 4B for PER=2).
// bf16->f32 load is the exact <<16 widening; store packs via _rn (same rounding as before).
template<int PER>
__global__ __launch_bounds__(256) void rownorm_k(__hip_bfloat16* __restrict__ buf,
                                                 int stride, float extra) {
  const int tid = threadIdx.x;
  __hip_bfloat16* p = buf + (size_t)blockIdx.x * stride + tid * PER;
  float v[PER];
  float ss = 0.f;
  if constexpr (PER == 8) {
    uint4 raw = *(const uint4*)p;
    unsigned int w[4] = {raw.x, raw.y, raw.z, raw.w};
    #pragma unroll
    for (int j = 0; j < 4; ++j) {
      v[2 * j]     = __builtin_bit_cast(float, w[j] << 16);
      v[2 * j + 1] = __builtin_bit_cast(float, w[j] & 0xffff0000u);
      ss += v[2 * j] * v[2 * j] + v[2 * j + 1] * v[2 * j + 1];
    }
  } else {
    unsigned int w = *(const unsigned int*)p;
    v[0] = __builtin_bit_cast(float, w << 16);
    v[1] = __builtin_bit_cast(float, w & 0xffff0000u);
    ss = v[0] * v[0] + v[1] * v[1];
  }
  #pragma unroll
  for (int off = 32; off >= 1; off >>= 1) ss += __shfl_xor(ss, off, 64);
  __shared__ float wsum[4];
  if ((tid & 63) == 0) wsum[tid >> 6] = ss;
  __syncthreads();
  float tot = wsum[0] + wsum[1] + wsum[2] + wsum[3];
  float sc = extra / (sqrtf(tot) + 1e-12f);
  if constexpr (PER == 8) {
    uint4 o;
    o.x = pkbf(v[0] * sc, v[1] * sc);
    o.y = pkbf(v[2] * sc, v[3] * sc);
    o.z = pkbf(v[4] * sc, v[5] * sc);
    o.w = pkbf(v[6] * sc, v[7] * sc);
    *(uint4*)p = o;
  } else {
    *(unsigned int*)p = pkbf(v[0] * sc, v[1] * sc);
  }
}

// ---------------- GEMM v2 (R5-proven): ring-3 LDS, counted-vmcnt pipeline --------------
// + T1 XCD-aware bijective block swizzle (nwg % 8 == 0 for all launches here):
// blocks on one XCD cover 8 contiguous M-panels (4MB A, L2-fit) x full N.
template<typename OutT>
__global__ __launch_bounds__(512, 2) void gemm3_k(const __hip_bfloat16* __restrict__ A,
                                                  const __hip_bfloat16* __restrict__ BT,
                                                  OutT* __restrict__ Cc,
                                                  int M, int N, int K) {
  __shared__ alignas(16) __hip_bfloat16 As[3][128 * 64];
  __shared__ alignas(16) __hip_bfloat16 Bs[3][256 * 64];
  const int tid  = threadIdx.x;
  const int gx   = (int)gridDim.x;
  const int lid  = (int)blockIdx.y * gx + (int)blockIdx.x;
  const int nwg  = gx * (int)gridDim.y;
  const int swz  = (lid & 7) * (nwg >> 3) + (lid >> 3);   // bijective: nwg % 8 == 0
  const int bm   = (swz / gx) * 128;
  const int bn   = (swz % gx) * 256;
  const int wave = tid >> 6, lane = tid & 63;
  const int wm = wave >> 2, wn = wave & 3;
  const int lm = lane & 15, quad = lane >> 4;
  const size_t Kz = (size_t)K;
  const int NT = K >> 6;

  const int srow = tid >> 3;                        // 0..63
  const int csw  = ((tid & 7) ^ (srow & 7)) * 8;    // swizzled 16B chunk offset
  const __hip_bfloat16* aSrc0 = A  + (size_t)(bm + srow) * Kz + csw;
  const __hip_bfloat16* aSrc1 = A  + (size_t)(bm + 64 + srow) * Kz + csw;
  const __hip_bfloat16* bSrc0 = BT + (size_t)(bn + srow) * Kz + csw;
  const __hip_bfloat16* bSrc1 = BT + (size_t)(bn + 64 + srow) * Kz + csw;
  const __hip_bfloat16* bSrc2 = BT + (size_t)(bn + 128 + srow) * Kz + csw;
  const __hip_bfloat16* bSrc3 = BT + (size_t)(bn + 192 + srow) * Kz + csw;

  auto stageA = [&](int slot, int koff) {
    async_copy16(aSrc0 + koff, As[slot] + tid * 8);
    async_copy16(aSrc1 + koff, As[slot] + (512 + tid) * 8);
  };
  auto stageB0 = [&](int slot, int koff) {
    async_copy16(bSrc0 + koff, Bs[slot] + tid * 8);
  };
  auto stageB123 = [&](int slot, int koff) {
    async_copy16(bSrc1 + koff, Bs[slot] + (512 + tid) * 8);
    async_copy16(bSrc2 + koff, Bs[slot] + (1024 + tid) * 8);
    async_copy16(bSrc3 + koff, Bs[slot] + (1536 + tid) * 8);
  };

  const int ch0 = ((quad) ^ (lm & 7)) * 8;
  const int ch1 = ((4 + quad) ^ (lm & 7)) * 8;
  const int arow = wm * 64 + lm;
  const int brow = wn * 64 + lm;

  f32x4 acc[4][4] = {};

  stageA(0, 0); stageB0(0, 0); stageB123(0, 0);
  if (NT > 1) { stageA(1, 64); stageB0(1, 64); stageB123(1, 64); }

  int s = 0;
  for (int t = 0; t < NT; ++t) {
    const int sn = (s + 2 > 2) ? (s - 1) : (s + 2);   // (s+2)%3
    const bool pre = (t + 2) < NT;
    const int koff = (t + 2) * 64;
    if (t + 1 < NT) asm volatile("s_waitcnt vmcnt(6)" ::: "memory");
    else            asm volatile("s_waitcnt vmcnt(0)" ::: "memory");
    __builtin_amdgcn_s_barrier();
    bf16x8 af[4][2], bf0[2][2];
    #pragma unroll
    for (int mf = 0; mf < 4; ++mf) {
      af[mf][0] = *(const bf16x8*)(As[s] + (arow + mf * 16) * 64 + ch0);
      af[mf][1] = *(const bf16x8*)(As[s] + (arow + mf * 16) * 64 + ch1);
    }
    #pragma unroll
    for (int nf = 0; nf < 2; ++nf) {
      bf0[nf][0] = *(const bf16x8*)(Bs[s] + (brow + nf * 16) * 64 + ch0);
      bf0[nf][1] = *(const bf16x8*)(Bs[s] + (brow + nf * 16) * 64 + ch1);
    }
    if (pre) { stageA(sn, koff); stageB0(sn, koff); }
    __builtin_amdgcn_s_barrier();
    __builtin_amdgcn_s_setprio(1);
    #pragma unroll
    for (int mf = 0; mf < 4; ++mf)
      #pragma unroll
      for (int nf = 0; nf < 2; ++nf) {
        acc[mf][nf] = __builtin_amdgcn_mfma_f32_16x16x32_bf16(af[mf][0], bf0[nf][0], acc[mf][nf], 0, 0, 0);
        acc[mf][nf] = __builtin_amdgcn_mfma_f32_16x16x32_bf16(af[mf][1], bf0[nf][1], acc[mf][nf], 0, 0, 0);
      }
    __builtin_amdgcn_s_setprio(0);
    __builtin_amdgcn_s_barrier();
    bf16x8 bf1[2][2];
    #pragma unroll
    for (int nf = 0; nf < 2; ++nf) {
      bf1[nf][0] = *(const bf16x8*)(Bs[s] + (brow + (nf + 2) * 16) * 64 + ch0);
      bf1[nf][1] = *(const bf16x8*)(Bs[s] + (brow + (nf + 2) * 16) * 64 + ch1);
    }
    if (pre) stageB123(sn, koff);
    __builtin_amdgcn_s_barrier();
    __builtin_amdgcn_s_setprio(1);
    #pragma unroll
    for (int mf = 0; mf < 4; ++mf)
      #pragma unroll
      for (int nf = 0; nf < 2; ++nf) {
        acc[mf][nf + 2] = __builtin_amdgcn_mfma_f32_16x16x32_bf16(af[mf][0], bf1[nf][0], acc[mf][nf + 2], 0, 0, 0);
        acc[mf][nf + 2] = __builtin_amdgcn_mfma_f32_16x16x32_bf16(af[mf][1], bf1[nf][1], acc[mf][nf + 2], 0, 0, 0);
      }
    __builtin_amdgcn_s_setprio(0);
    s = (s == 2) ? 0 : s + 1;
  }

  const int r0 = quad * 4;
  #pragma unroll
  for (int mf = 0; mf < 4; ++mf)
    #pragma unroll
    for (int nf = 0; nf < 4; ++nf)
      #pragma unroll
      for (int r = 0; r < 4; ++r) {
        int gr = bm + wm * 64 + mf * 16 + r0 + r;
        int gc = bn + wn * 64 + nf * 16 + lm;
        float v = acc[mf][nf][r];
        if constexpr (__is_same(OutT, float))
          Cc[(size_t)gr * N + gc] = v;
        else
          Cc[(size_t)gr * N + gc] = __float2bfloat16(v);
      }
}

// ---------------- flash attention v6 (FROZEN; R5/R9-proven 110us): triangle-folded ----
// 256-thread blocks (4 waves x 32 q-rows, Q-tile 128), 120 VGPR, 64KB LDS, 2 blocks/CU.
// Block processes q-tile PAIR {15-p, p}: uniform 36 K-tiles/block, 512 blocks.
// Swapped QK^T (32x32x16), P fully in-register via bit-2/3-swapped V layout, V staged
// in LDS. Failed variants (do not retry): kv-split waves (R6 +11%), V-from-global
// (R8 3x), single-V+unfold (R10 +41%).
__global__ __launch_bounds__(256, 2) void attn_k(const __hip_bfloat16* __restrict__ q,
                                                 const __hip_bfloat16* __restrict__ kv,
                                                 const __hip_bfloat16* __restrict__ vt,
                                                 __hip_bfloat16* __restrict__ y) {
  const int pp = blockIdx.x;      // pair index 0..7
  const int h  = blockIdx.y;
  const int b  = blockIdx.z;
  const int g  = h >> 2;
  const int tid = threadIdx.x;
  const int wave = tid >> 6, lane = tid & 63;
  const int l31 = lane & 31, hi = lane >> 5;

  __shared__ alignas(16) __hip_bfloat16 Ks[2][64 * 128];
  __shared__ alignas(16) __hip_bfloat16 Vts[2][128 * 64];

  const __hip_bfloat16* kb = kv + (size_t)b * T_ * KVD_ + g * HD_;
  const __hip_bfloat16* vb = vt + (size_t)(b * 4 + g) * HD_ * T_;

  auto stage = [&](int buf, int jt) {
    const size_t j1 = (size_t)jt * 64;
    #pragma unroll
    for (int e = 0; e < 4; ++e) {
      int idx = tid + e * 256;
      int row = idx >> 4, c = idx & 15;
      async_copy16(kb + (j1 + row) * KVD_ + ((c ^ (row & 15)) * 8), Ks[buf] + idx * 8);
    }
    #pragma unroll
    for (int e = 0; e < 4; ++e) {
      int idx = tid + e * 256;
      int row = idx >> 3, c = idx & 7;
      async_copy16(vb + (size_t)row * T_ + j1 + ((c ^ (row & 7)) * 8), Vts[buf] + idx * 8);
    }
  };

  stage(0, 0);  // first tile of first segment

  #pragma unroll
  for (int seg = 0; seg < 2; ++seg) {
    const int qt = seg ? pp : (15 - pp);
    const int qbase = qt * 128 + wave * 32;
    const int qmax = qbase + 31;
    const int ntiles = 2 * qt + 2;

    const __hip_bfloat16* qrow = q + ((size_t)b * T_ + qbase + l31) * C_ + h * HD_;
    bf16x8 qf[8];
    #pragma unroll
    for (int kc = 0; kc < 8; ++kc)
      qf[kc] = *(const bf16x8*)(qrow + kc * 16 + hi * 8);

    __syncthreads();  // tile 0 of this segment staged (barrier drains vmcnt)

    f32x16 o_acc[4] = {};
    float l_acc = 0.f;

    for (int it = 0; it < ntiles; ++it) {
      const int cur = it & 1;
      if (it + 1 < ntiles) stage(cur ^ 1, it + 1);
      const int j0 = it * 64;
      if (j0 <= qmax) {
        f32x16 st0 = {}, st1 = {};
        __builtin_amdgcn_s_setprio(1);
        #pragma unroll
        for (int kc = 0; kc < 8; ++kc) {
          const int cs0 = (((2 * kc + hi) ^ (l31 & 15)) * 8);
          bf16x8 k0 = *(const bf16x8*)(Ks[cur] + l31 * 128 + cs0);
          bf16x8 k1 = *(const bf16x8*)(Ks[cur] + (32 + l31) * 128 + cs0);
          st0 = __builtin_amdgcn_mfma_f32_32x32x16_bf16(k0, qf[kc], st0, 0, 0, 0);
          st1 = __builtin_amdgcn_mfma_f32_32x32x16_bf16(k1, qf[kc], st1, 0, 0, 0);
        }
        __builtin_amdgcn_s_setprio(0);
        const int qd = qbase + l31 - j0;
        if (j0 + 63 <= qbase) {
          #pragma unroll
          for (int r = 0; r < 16; ++r) {
            float p0 = __expf(st0[r]);
            float p1 = __expf(st1[r]);
            st0[r] = p0; st1[r] = p1;
            l_acc += p0 + p1;
          }
        } else {
          #pragma unroll
          for (int r = 0; r < 16; ++r) {
            const int ofs = (r & 3) + 8 * (r >> 2) + 4 * hi;
            float p0 = (ofs <= qd) ? __expf(st0[r]) : 0.f;
            float p1 = (ofs + 32 <= qd) ? __expf(st1[r]) : 0.f;
            st0[r] = p0; st1[r] = p1;
            l_acc += p0 + p1;
          }
        }
        unsigned int W[8][2];
        #pragma unroll
        for (int q4 = 0; q4 < 4; ++q4) {
          W[q4][0]     = pkbf(st0[4 * q4 + 0], st0[4 * q4 + 1]);
          W[q4][1]     = pkbf(st0[4 * q4 + 2], st0[4 * q4 + 3]);
          W[4 + q4][0] = pkbf(st1[4 * q4 + 0], st1[4 * q4 + 1]);
          W[4 + q4][1] = pkbf(st1[4 * q4 + 2], st1[4 * q4 + 3]);
        }
        __builtin_amdgcn_s_setprio(1);
        #pragma unroll
        for (int kc = 0; kc < 4; ++kc) {
          u32x4 pw;
          pw[0] = W[2 * kc][0]; pw[1] = W[2 * kc][1];
          pw[2] = W[2 * kc + 1][0]; pw[3] = W[2 * kc + 1][1];
          bf16x8 pf = __builtin_bit_cast(bf16x8, pw);
          const int csv = (((2 * kc + hi) ^ (l31 & 7)) * 8);
          #pragma unroll
          for (int ct = 0; ct < 4; ++ct) {
            bf16x8 vf = *(const bf16x8*)(Vts[cur] + (ct * 32 + l31) * 64 + csv);
            o_acc[ct] = __builtin_amdgcn_mfma_f32_32x32x16_bf16(pf, vf, o_acc[ct], 0, 0, 0);
          }
        }
        __builtin_amdgcn_s_setprio(0);
      }
      __syncthreads();
    }

    if (seg == 0) stage(0, 0);

    float lsum = l_acc + __shfl_xor(l_acc, 32, 64);
    float oinv[16];
    #pragma unroll
    for (int r = 0; r < 16; ++r) {
      int row = (r & 3) + 8 * (r >> 2) + 4 * hi;
      oinv[r] = 1.0f / __shfl(lsum, row, 64);
    }
    __hip_bfloat16* yb = y + ((size_t)b * T_ + qbase) * C_ + h * HD_ + l31;
    #pragma unroll
    for (int ct = 0; ct < 4; ++ct)
      #pragma unroll
      for (int r = 0; r < 16; ++r) {
        int row = (r & 3) + 8 * (r >> 2) + 4 * hi;
        yb[(size_t)row * C_ + ct * 32] = __float2bfloat16(o_acc[ct][r] * oinv[r]);
      }
  }
}

extern "C" void kernel_launch(void* const* d_in, const int* in_sizes, int n_in,
                              void* d_out, int out_size, void* d_ws, size_t ws_size,
                              hipStream_t stream) {
  (void)in_sizes; (void)n_in; (void)out_size; (void)ws_size;
  const float* x     = (const float*)d_in[0];
  const float* Wq    = (const float*)d_in[1];
  const float* Wkv   = (const float*)d_in[2];
  const float* Wproj = (const float*)d_in[3];
  char* ws = (char*)d_ws;
  __hip_bfloat16* xb     = (__hip_bfloat16*)(ws);               // 32 MB (reused as y)
  __hip_bfloat16* WqT    = (__hip_bfloat16*)(ws + 33554432);    //  8 MB
  __hip_bfloat16* WkvT   = (__hip_bfloat16*)(ws + 41943040);    //  4 MB
  __hip_bfloat16* WprojT = (__hip_bfloat16*)(ws + 46137344);    //  8 MB
  __hip_bfloat16* qn     = (__hip_bfloat16*)(ws + 54525952);    // 32 MB
  __hip_bfloat16* kvb    = (__hip_bfloat16*)(ws + 88080384);    // 16 MB
  __hip_bfloat16* y      = xb;                                  // alias: xb dead after kv-gemm
  __hip_bfloat16* vt     = (__hip_bfloat16*)d_out;              // 16 MB scratch in d_out
  float* out             = (float*)d_out;

  f32_to_bf16_k<<<16384, 256, 0, stream>>>(x, xb, 4194304);
  transpose_f32_bf16_k<<<dim3(64, 64), dim3(32, 8), 0, stream>>>(Wq, WqT, 2048, 2048);
  transpose_f32_bf16_k<<<dim3(32, 64), dim3(32, 8), 0, stream>>>(Wkv, WkvT, 2048, 1024);
  transpose_f32_bf16_k<<<dim3(64, 64), dim3(32, 8), 0, stream>>>(Wproj, WprojT, 2048, 2048);
  gemm3_k<__hip_bfloat16><<<dim3(8, 64), 512, 0, stream>>>(xb, WqT, qn, 8192, 2048, 2048);
  gemm3_k<__hip_bfloat16><<<dim3(4, 64), 512, 0, stream>>>(xb, WkvT, kvb, 8192, 1024, 2048);
  rownorm_k<8><<<8192, 256, 0, stream>>>(qn, 2048, 0.08838834764831845f);  // 1/sqrt(HD) folded
  rownorm_k<2><<<8192, 256, 0, stream>>>(kvb, 1024, 1.0f);
  vtrans_k<<<dim3(64, 4, 16), dim3(32, 8), 0, stream>>>(kvb, vt);
  attn_k<<<dim3(8, 16, 4), 256, 0, stream>>>(qn, kvb, vt, y);
  gemm3_k<float><<<dim3(8, 64), 512, 0, stream>>>(y, WprojT, out, 8192, 2048, 2048);
}